// Round 2
// baseline (24763.118 us; speedup 1.0000x reference)
//
#include <hip/hip_runtime.h>

// ---------------------------------------------------------------------------
// OmniAnomaly forward: Qnet (GRU + dense + planar flows) -> Pnet (GRU + dense)
// B=256, W=128, IN=128, H=1024, Z=128, D=1024, OUT=128, K=3 flows
// Device tensors are FP32 (reference dtype). We convert weights/x to bf16 once
// per launch for MFMA; fp32 accumulation + fp32 master GRU states; fp32 output.
// ---------------------------------------------------------------------------

typedef __bf16 bf16;
typedef __bf16 bf16x4 __attribute__((ext_vector_type(4)));
typedef __bf16 bf16x8 __attribute__((ext_vector_type(8)));
typedef float  f32x4  __attribute__((ext_vector_type(4)));

static constexpr int CB   = 256;   // batch
static constexpr int CW   = 128;   // timesteps
static constexpr int CIN  = 128;
static constexpr int CH   = 1024;  // GRU hidden
static constexpr int CZ   = 128;
static constexpr int CD   = 1024;
static constexpr int COUT = 128;
static constexpr int CNK  = 3;     // planar flows

#define DEV static __device__ __forceinline__

DEV float sigmoidf_(float x) { return 1.0f / (1.0f + expf(-x)); }
DEV float softplusf_(float x) { return x > 20.0f ? x : log1pf(expf(x)); }

DEV bf16x8 ldfrag(const bf16* p) { return *reinterpret_cast<const bf16x8*>(p); }

#define MFMA(a, b, c) __builtin_amdgcn_mfma_f32_16x16x32_bf16((a), (b), (c), 0, 0, 0)

// ---------------------------------------------------------------------------
// fp32 -> bf16 conversion (n divisible by 4)
// ---------------------------------------------------------------------------
__global__ void k_cvt(const float* __restrict__ src, bf16* __restrict__ dst, int n)
{
    int i = (blockIdx.x * blockDim.x + threadIdx.x) * 4;
    if (i < n) {
        float4 v = *reinterpret_cast<const float4*>(src + i);
        bf16x4 o;
        o[0] = (bf16)v.x; o[1] = (bf16)v.y; o[2] = (bf16)v.z; o[3] = (bf16)v.w;
        *reinterpret_cast<bf16x4*>(dst + i) = o;
    }
}

// ---------------------------------------------------------------------------
// Fused GRU step:  e_new = (1-u)*n + u*e_prev
// Tile 64x64 (M x N_hidden), 4 waves of 32x32, 4 accumulator groups.
// Grid: (CH/64, CB/64) = (16, 4)
// ---------------------------------------------------------------------------
__launch_bounds__(256)
__global__ void k_gru(const bf16* __restrict__ X, long x_stride,     // A1 [B x 128] bf16
                      const bf16* __restrict__ Eprev_bf,             // A2 [B x H] bf16
                      const float* __restrict__ Eprev_f,
                      const bf16* __restrict__ Wih,                  // [3H x 128] bf16
                      const bf16* __restrict__ Whh,                  // [3H x H] bf16
                      const float* __restrict__ bih,                 // fp32
                      const float* __restrict__ bhh,
                      float* __restrict__ Eout_f,
                      bf16* __restrict__ Eout_bf)
{
    const int tid  = threadIdx.x;
    const int lane = tid & 63;
    const int wave = tid >> 6;
    const int m0   = blockIdx.y * 64 + (wave >> 1) * 32;
    const int n0   = blockIdx.x * 64 + (wave & 1) * 32;
    const int lr   = lane & 15;
    const int lk   = (lane >> 4) * 8;

    // groups: 0=r (full K), 1=z (full K), 2=n_input, 3=n_hidden
    f32x4 acc[4][2][2] = {};

    // ---- input part: K = 128 over X, Wih ----
    for (int k = 0; k < CIN; k += 32) {
        bf16x8 a[2];
        a[0] = ldfrag(X + (long)(m0 + lr) * x_stride + k + lk);
        a[1] = ldfrag(X + (long)(m0 + 16 + lr) * x_stride + k + lk);
#pragma unroll
        for (int g = 0; g < 3; ++g) {
            const int grp = (g == 2) ? 2 : g;
            const bf16* wb = Wih + ((long)g * CH + n0 + lr) * CIN + k + lk;
            bf16x8 b[2];
            b[0] = ldfrag(wb);
            b[1] = ldfrag(wb + (long)16 * CIN);
#pragma unroll
            for (int mi = 0; mi < 2; ++mi)
#pragma unroll
                for (int ni = 0; ni < 2; ++ni)
                    acc[grp][mi][ni] = MFMA(a[mi], b[ni], acc[grp][mi][ni]);
        }
    }

    // ---- hidden part: K = 1024 over Eprev, Whh ----
#pragma unroll 2
    for (int k = 0; k < CH; k += 32) {
        bf16x8 a[2];
        a[0] = ldfrag(Eprev_bf + (long)(m0 + lr) * CH + k + lk);
        a[1] = ldfrag(Eprev_bf + (long)(m0 + 16 + lr) * CH + k + lk);
#pragma unroll
        for (int g = 0; g < 3; ++g) {
            const int grp = (g == 2) ? 3 : g;
            const bf16* wb = Whh + ((long)g * CH + n0 + lr) * CH + k + lk;
            bf16x8 b[2];
            b[0] = ldfrag(wb);
            b[1] = ldfrag(wb + (long)16 * CH);
#pragma unroll
            for (int mi = 0; mi < 2; ++mi)
#pragma unroll
                for (int ni = 0; ni < 2; ++ni)
                    acc[grp][mi][ni] = MFMA(a[mi], b[ni], acc[grp][mi][ni]);
        }
    }

    // ---- epilogue: gate math, state update ----
#pragma unroll
    for (int mi = 0; mi < 2; ++mi)
#pragma unroll
        for (int ni = 0; ni < 2; ++ni)
#pragma unroll
            for (int i = 0; i < 4; ++i) {
                const int row = m0 + mi * 16 + (lane >> 4) * 4 + i;
                const int col = n0 + ni * 16 + lr;
                float gr = acc[0][mi][ni][i] + bih[col] + bhh[col];
                float gz = acc[1][mi][ni][i] + bih[CH + col] + bhh[CH + col];
                float gi = acc[2][mi][ni][i] + bih[2 * CH + col];
                float gh = acc[3][mi][ni][i] + bhh[2 * CH + col];
                float r = sigmoidf_(gr);
                float u = sigmoidf_(gz);
                float n = tanhf(gi + r * gh);
                float ep = Eprev_f[(long)row * CH + col];
                float en = (1.0f - u) * n + u * ep;
                Eout_f[(long)row * CH + col] = en;
                Eout_bf[(long)row * CH + col] = (bf16)en;
            }
}

// ---------------------------------------------------------------------------
// Plain linear: Out(bf16) = [A1|A2] @ Wm^T + bias   (A1 optional, K1 may be 0)
// Tile 64x64, grid (N/64, CB/64)
// ---------------------------------------------------------------------------
__launch_bounds__(256)
__global__ void k_lin(const bf16* __restrict__ A1, int K1, long a1_stride,
                      const bf16* __restrict__ A2, int K2,
                      const bf16* __restrict__ Wm, int ldw,
                      const float* __restrict__ bias,
                      bf16* __restrict__ Outbf, int ldo)
{
    const int tid  = threadIdx.x;
    const int lane = tid & 63;
    const int wave = tid >> 6;
    const int m0 = blockIdx.y * 64 + (wave >> 1) * 32;
    const int n0 = blockIdx.x * 64 + (wave & 1) * 32;
    const int lr = lane & 15;
    const int lk = (lane >> 4) * 8;

    f32x4 acc[2][2] = {};

    for (int k = 0; k < K1; k += 32) {
        bf16x8 a[2];
        a[0] = ldfrag(A1 + (long)(m0 + lr) * a1_stride + k + lk);
        a[1] = ldfrag(A1 + (long)(m0 + 16 + lr) * a1_stride + k + lk);
        const bf16* wb = Wm + (long)(n0 + lr) * ldw + k + lk;
        bf16x8 b[2];
        b[0] = ldfrag(wb);
        b[1] = ldfrag(wb + (long)16 * ldw);
#pragma unroll
        for (int mi = 0; mi < 2; ++mi)
#pragma unroll
            for (int ni = 0; ni < 2; ++ni)
                acc[mi][ni] = MFMA(a[mi], b[ni], acc[mi][ni]);
    }
#pragma unroll 2
    for (int k = 0; k < K2; k += 32) {
        bf16x8 a[2];
        a[0] = ldfrag(A2 + (long)(m0 + lr) * K2 + k + lk);
        a[1] = ldfrag(A2 + (long)(m0 + 16 + lr) * K2 + k + lk);
        const bf16* wb = Wm + (long)(n0 + lr) * ldw + K1 + k + lk;
        bf16x8 b[2];
        b[0] = ldfrag(wb);
        b[1] = ldfrag(wb + (long)16 * ldw);
#pragma unroll
        for (int mi = 0; mi < 2; ++mi)
#pragma unroll
            for (int ni = 0; ni < 2; ++ni)
                acc[mi][ni] = MFMA(a[mi], b[ni], acc[mi][ni]);
    }

#pragma unroll
    for (int mi = 0; mi < 2; ++mi)
#pragma unroll
        for (int ni = 0; ni < 2; ++ni)
#pragma unroll
            for (int i = 0; i < 4; ++i) {
                const int row = m0 + mi * 16 + (lane >> 4) * 4 + i;
                const int col = n0 + ni * 16 + lr;
                float v = acc[mi][ni][i] + bias[col];
                Outbf[(long)row * ldo + col] = (bf16)v;
            }
}

// ---------------------------------------------------------------------------
// Two-head linear tail (K = 1024), fp32 outputs:
//   MODE 0 (Qnet): mu = A@Wa^T+ba ; lv = softplus(A@Wb^T+bb)
//                  z = mu + exp(0.5*lv)*eps ; write mu(f32), lv(f32), z(f32 tmp)
//   MODE 1 (Pnet): out(f32) = (A@Wa^T+ba) + softplus(A@Wb^T+bb)*eps
// Grid (128/64, CB/64) = (2, 4)
// ---------------------------------------------------------------------------
template <int MODE>
__launch_bounds__(256)
__global__ void k_tail2(const bf16* __restrict__ A,                  // [B x D] bf16
                        const bf16* __restrict__ Wa, const bf16* __restrict__ Wb, // [128 x D] bf16
                        const float* __restrict__ ba, const float* __restrict__ bb,
                        const float* __restrict__ EPS, long eps_stride,
                        float* __restrict__ O1, long o1_stride,
                        float* __restrict__ O2, long o2_stride,
                        float* __restrict__ Ztmp)
{
    const int tid  = threadIdx.x;
    const int lane = tid & 63;
    const int wave = tid >> 6;
    const int m0 = blockIdx.y * 64 + (wave >> 1) * 32;
    const int n0 = blockIdx.x * 64 + (wave & 1) * 32;
    const int lr = lane & 15;
    const int lk = (lane >> 4) * 8;

    f32x4 aa[2][2] = {}, ab[2][2] = {};

#pragma unroll 2
    for (int k = 0; k < CD; k += 32) {
        bf16x8 a[2];
        a[0] = ldfrag(A + (long)(m0 + lr) * CD + k + lk);
        a[1] = ldfrag(A + (long)(m0 + 16 + lr) * CD + k + lk);
        const bf16* wa = Wa + (long)(n0 + lr) * CD + k + lk;
        const bf16* wbp = Wb + (long)(n0 + lr) * CD + k + lk;
        bf16x8 b0[2], b1[2];
        b0[0] = ldfrag(wa);  b0[1] = ldfrag(wa + (long)16 * CD);
        b1[0] = ldfrag(wbp); b1[1] = ldfrag(wbp + (long)16 * CD);
#pragma unroll
        for (int mi = 0; mi < 2; ++mi)
#pragma unroll
            for (int ni = 0; ni < 2; ++ni) {
                aa[mi][ni] = MFMA(a[mi], b0[ni], aa[mi][ni]);
                ab[mi][ni] = MFMA(a[mi], b1[ni], ab[mi][ni]);
            }
    }

#pragma unroll
    for (int mi = 0; mi < 2; ++mi)
#pragma unroll
        for (int ni = 0; ni < 2; ++ni)
#pragma unroll
            for (int i = 0; i < 4; ++i) {
                const int row = m0 + mi * 16 + (lane >> 4) * 4 + i;
                const int col = n0 + ni * 16 + lr;
                float m = aa[mi][ni][i] + ba[col];
                float s = ab[mi][ni][i] + bb[col];
                float e = EPS[(long)row * eps_stride + col];
                if constexpr (MODE == 0) {
                    float lv = softplusf_(s);
                    float z  = m + expf(0.5f * lv) * e;
                    O1[(long)row * o1_stride + col] = m;
                    O2[(long)row * o2_stride + col] = lv;
                    Ztmp[(long)row * CZ + col] = z;
                } else {
                    float sg = softplusf_(s);
                    O1[(long)row * o1_stride + col] = m + sg * e;
                }
            }
}

// ---------------------------------------------------------------------------
// Planar flows (K=3) + LGSSM linear (all fp32 math, fp32 weights):
//   z = z + up[k]*tanh(z@Wp[k]^T + bp[k]);  zt = z@Wlg^T + blg
// 2 rows per 256-thread WG. Grid CB/2 = 128.
// Outputs: Zprev (bf16, next-step k_lin A operand), ZtOut (bf16, Pnet GRU A).
// ---------------------------------------------------------------------------
__launch_bounds__(256)
__global__ void k_flows(const float* __restrict__ Ztmp,
                        const float* __restrict__ Wp, const float* __restrict__ bp,
                        const float* __restrict__ up,
                        const float* __restrict__ Wlg, const float* __restrict__ blg,
                        bf16* __restrict__ Zprev, bf16* __restrict__ ZtOut)
{
    const int tid = threadIdx.x;
    const int r = tid >> 7;          // 0..1
    const int c = tid & 127;         // 0..127
    const int row = blockIdx.x * 2 + r;

    __shared__ float zl[2][CZ];
    zl[r][c] = Ztmp[(long)row * CZ + c];
    __syncthreads();

    for (int k = 0; k < CNK; ++k) {
        const float* wrow = Wp + ((long)k * CZ + c) * CZ;
        float s = bp[k * CZ + c];
#pragma unroll 8
        for (int j = 0; j < CZ; j += 4) {
            float4 wv = *reinterpret_cast<const float4*>(wrow + j);
            s += zl[r][j] * wv.x + zl[r][j + 1] * wv.y
               + zl[r][j + 2] * wv.z + zl[r][j + 3] * wv.w;
        }
        float zn = zl[r][c] + up[k] * tanhf(s);
        __syncthreads();
        zl[r][c] = zn;
        __syncthreads();
    }

    // zt = z @ Wlg^T + blg
    const float* wrow = Wlg + (long)c * CZ;
    float s = blg[c];
#pragma unroll 8
    for (int j = 0; j < CZ; j += 4) {
        float4 wv = *reinterpret_cast<const float4*>(wrow + j);
        s += zl[r][j] * wv.x + zl[r][j + 1] * wv.y
           + zl[r][j + 2] * wv.z + zl[r][j + 3] * wv.w;
    }
    Zprev[(long)row * CZ + c] = (bf16)zl[r][c];
    ZtOut[(long)row * CZ + c] = (bf16)s;
}

// ---------------------------------------------------------------------------
// Host driver
// ---------------------------------------------------------------------------
extern "C" void kernel_launch(void* const* d_in, const int* in_sizes, int n_in,
                              void* d_out, int out_size, void* d_ws, size_t ws_size,
                              hipStream_t stream)
{
    const float* x      = (const float*)d_in[0];
    const float* eps_q  = (const float*)d_in[1];
    const float* eps_p  = (const float*)d_in[2];
    const float* Wih_q  = (const float*)d_in[3];
    const float* Whh_q  = (const float*)d_in[4];
    const float* bih_q  = (const float*)d_in[5];
    const float* bhh_q  = (const float*)d_in[6];
    const float* Wd_q   = (const float*)d_in[7];
    const float* bd_q   = (const float*)d_in[8];
    const float* Wmu_q  = (const float*)d_in[9];
    const float* bmu_q  = (const float*)d_in[10];
    const float* Wsig_q = (const float*)d_in[11];
    const float* bsig_q = (const float*)d_in[12];
    const float* Wp     = (const float*)d_in[13];
    const float* bp     = (const float*)d_in[14];
    const float* up     = (const float*)d_in[15];
    const float* Wlg    = (const float*)d_in[16];
    const float* blg    = (const float*)d_in[17];
    const float* Wih_p  = (const float*)d_in[18];
    const float* Whh_p  = (const float*)d_in[19];
    const float* bih_p  = (const float*)d_in[20];
    const float* bhh_p  = (const float*)d_in[21];
    const float* Wd_p   = (const float*)d_in[22];
    const float* bd_p   = (const float*)d_in[23];
    const float* Wmu_p  = (const float*)d_in[24];
    const float* bmu_p  = (const float*)d_in[25];
    const float* Wsig_p = (const float*)d_in[26];
    const float* bsig_p = (const float*)d_in[27];

    float* out_o  = (float*)d_out;                      // [B, W, OUT]
    float* out_mu = out_o + (size_t)CB * CW * COUT;     // [B, W, Z]
    float* out_lv = out_mu + (size_t)CB * CW * CZ;      // [B, W, Z]

    // workspace carve
    char* wp_ = (char*)d_ws;
    auto carve = [&](size_t bytes) -> void* {
        void* q = (void*)wp_;
        wp_ += (bytes + 255) & ~(size_t)255;
        return q;
    };
    float* e_f[2]; bf16* e_b[2]; float* d_f[2]; bf16* d_b[2];
    e_f[0] = (float*)carve((size_t)CB * CH * 4);
    e_f[1] = (float*)carve((size_t)CB * CH * 4);
    e_b[0] = (bf16*)carve((size_t)CB * CH * 2);
    e_b[1] = (bf16*)carve((size_t)CB * CH * 2);
    d_f[0] = (float*)carve((size_t)CB * CH * 4);
    d_f[1] = (float*)carve((size_t)CB * CH * 4);
    d_b[0] = (bf16*)carve((size_t)CB * CH * 2);
    d_b[1] = (bf16*)carve((size_t)CB * CH * 2);
    bf16*  zprev = (bf16*)carve((size_t)CB * CZ * 2);
    float* ztmp  = (float*)carve((size_t)CB * CZ * 4);
    bf16*  dvec  = (bf16*)carve((size_t)CB * CD * 2);
    bf16*  ztseq = (bf16*)carve((size_t)CW * CB * CZ * 2);
    bf16*  x_b    = (bf16*)carve((size_t)CB * CW * CIN * 2);
    bf16*  Wih_qb = (bf16*)carve((size_t)3 * CH * CIN * 2);
    bf16*  Whh_qb = (bf16*)carve((size_t)3 * CH * CH * 2);
    bf16*  Wd_qb  = (bf16*)carve((size_t)CD * (CZ + CH) * 2);
    bf16*  Wmu_qb = (bf16*)carve((size_t)CZ * CD * 2);
    bf16*  Wsg_qb = (bf16*)carve((size_t)CZ * CD * 2);
    bf16*  Wih_pb = (bf16*)carve((size_t)3 * CH * CZ * 2);
    bf16*  Whh_pb = (bf16*)carve((size_t)3 * CH * CH * 2);
    bf16*  Wd_pb  = (bf16*)carve((size_t)CD * CH * 2);
    bf16*  Wmu_pb = (bf16*)carve((size_t)COUT * CD * 2);
    bf16*  Wsg_pb = (bf16*)carve((size_t)COUT * CD * 2);

    hipMemsetAsync(e_f[0], 0, (size_t)CB * CH * 4, stream);
    hipMemsetAsync(e_b[0], 0, (size_t)CB * CH * 2, stream);
    hipMemsetAsync(d_f[0], 0, (size_t)CB * CH * 4, stream);
    hipMemsetAsync(d_b[0], 0, (size_t)CB * CH * 2, stream);
    hipMemsetAsync(zprev, 0, (size_t)CB * CZ * 2, stream);

    // ---- convert weights + x to bf16 ----
    auto cvt = [&](const float* s, bf16* d, size_t n) {
        k_cvt<<<dim3((unsigned)((n / 4 + 255) / 256)), dim3(256), 0, stream>>>(s, d, (int)n);
    };
    cvt(x,      x_b,    (size_t)CB * CW * CIN);
    cvt(Wih_q,  Wih_qb, (size_t)3 * CH * CIN);
    cvt(Whh_q,  Whh_qb, (size_t)3 * CH * CH);
    cvt(Wd_q,   Wd_qb,  (size_t)CD * (CZ + CH));
    cvt(Wmu_q,  Wmu_qb, (size_t)CZ * CD);
    cvt(Wsig_q, Wsg_qb, (size_t)CZ * CD);
    cvt(Wih_p,  Wih_pb, (size_t)3 * CH * CZ);
    cvt(Whh_p,  Whh_pb, (size_t)3 * CH * CH);
    cvt(Wd_p,   Wd_pb,  (size_t)CD * CH);
    cvt(Wmu_p,  Wmu_pb, (size_t)COUT * CD);
    cvt(Wsig_p, Wsg_pb, (size_t)COUT * CD);

    const dim3 blk(256);
    const dim3 g_gemm(CH / 64, CB / 64);   // (16,4)
    const dim3 g_tail(CZ / 64, CB / 64);   // (2,4)

    // ---- Qnet pass ----
    for (int t = 0; t < CW; ++t) {
        const int pi = t & 1, po = pi ^ 1;
        k_gru<<<g_gemm, blk, 0, stream>>>(x_b + (long)t * CIN, (long)CW * CIN,
                                          e_b[pi], e_f[pi],
                                          Wih_qb, Whh_qb, bih_q, bhh_q,
                                          e_f[po], e_b[po]);
        k_lin<<<g_gemm, blk, 0, stream>>>(zprev, CZ, (long)CZ,
                                          e_b[po], CH,
                                          Wd_qb, CZ + CH, bd_q, dvec, CD);
        k_tail2<0><<<g_tail, blk, 0, stream>>>(dvec, Wmu_qb, Wsg_qb, bmu_q, bsig_q,
                                               eps_q + (long)t * CZ, (long)CW * CZ,
                                               out_mu + (long)t * CZ, (long)CW * CZ,
                                               out_lv + (long)t * CZ, (long)CW * CZ,
                                               ztmp);
        k_flows<<<dim3(CB / 2), blk, 0, stream>>>(ztmp, Wp, bp, up, Wlg, blg,
                                                  zprev, ztseq + (size_t)t * CB * CZ);
    }

    // ---- Pnet pass ----
    for (int t = 0; t < CW; ++t) {
        const int pi = t & 1, po = pi ^ 1;
        k_gru<<<g_gemm, blk, 0, stream>>>(ztseq + (size_t)t * CB * CZ, (long)CZ,
                                          d_b[pi], d_f[pi],
                                          Wih_pb, Whh_pb, bih_p, bhh_p,
                                          d_f[po], d_b[po]);
        k_lin<<<g_gemm, blk, 0, stream>>>(nullptr, 0, 0,
                                          d_b[po], CH,
                                          Wd_pb, CH, bd_p, dvec, CD);
        k_tail2<1><<<g_tail, blk, 0, stream>>>(dvec, Wmu_pb, Wsg_pb, bmu_p, bsig_p,
                                               eps_p + (long)t * COUT, (long)CW * COUT,
                                               out_o + (long)t * COUT, (long)CW * COUT,
                                               nullptr, 0, nullptr);
    }
}

// Round 4
// 24246.727 us; speedup vs baseline: 1.0213x; 1.0213x over previous
//
#include <hip/hip_runtime.h>

// ---------------------------------------------------------------------------
// OmniAnomaly forward, persistent mega-kernel with SOFTWARE grid barrier
// (hipLaunchCooperativeKernel failed silently in this harness in round 3).
// B=256, W=128, IN=128, H=1024, Z=128, D=1024, OUT=128, K=3 flows
// FP32 device tensors; weights pre-converted to bf16 for MFMA; fp32 master
// GRU states with bf16 shadows; fp32 accumulation everywhere.
// Grid: 256 WGs x 256 threads (1/CU, all co-resident), 6 barriers/timestep.
// ---------------------------------------------------------------------------

typedef __bf16 bf16;
typedef __bf16 bf16x4 __attribute__((ext_vector_type(4)));
typedef __bf16 bf16x8 __attribute__((ext_vector_type(8)));
typedef float  f32x4  __attribute__((ext_vector_type(4)));

static constexpr int CB   = 256;
static constexpr int CW   = 128;
static constexpr int CIN  = 128;
static constexpr int CH   = 1024;
static constexpr int CZ   = 128;
static constexpr int CD   = 1024;
static constexpr int COUT = 128;
static constexpr int NWG  = 256;   // grid size

#define DEV static __device__ __forceinline__

DEV float sigmoidf_(float x) { return 1.0f / (1.0f + expf(-x)); }
DEV float softplusf_(float x) { return x > 20.0f ? x : log1pf(expf(x)); }
DEV bf16x8 ldfrag(const bf16* p) { return *reinterpret_cast<const bf16x8*>(p); }

#define MFMA(a, b, c) __builtin_amdgcn_mfma_f32_16x16x32_bf16((a), (b), (c), 0, 0, 0)

struct Prm {
    const float *x, *eps_q, *eps_p;
    const float *bih_q, *bhh_q, *bd_q, *bmu_q, *bsig_q;
    const float *Wp, *bp, *up, *Wlg, *blg;
    const float *bih_p, *bhh_p, *bd_p, *bmu_p, *bsig_p;
    const bf16 *x_b, *Wih_qb, *Whh_qb, *Wd_qb, *Wmu_qb, *Wsg_qb;
    const bf16 *Wih_pb, *Whh_pb, *Wd_pb, *Wmu_pb, *Wsg_pb;
    float *e_f0, *e_f1; bf16 *e_b0, *e_b1;
    float *d_f0, *d_f1; bf16 *d_b0, *d_b1;
    bf16 *zprev_b, *zt_b; float *ztmp_f;
    bf16 *dvec_b, *ddvec_b;
    unsigned *bar;
    float *out_o, *out_mu, *out_lv;
};

// ---------------------------------------------------------------------------
// Software grid barrier: monotonically increasing counter, agent scope.
// bar is memset to 0 at the start of every kernel_launch (graph-replayed),
// so each call sees a fresh counter -> deterministic.
// ---------------------------------------------------------------------------
DEV void gbar(unsigned* bar, unsigned& target)
{
    __syncthreads();                       // all block writes issued
    if (threadIdx.x == 0) {
        target += NWG;
        __threadfence();                   // device-scope release of block's writes
        __hip_atomic_fetch_add(bar, 1u, __ATOMIC_RELEASE, __HIP_MEMORY_SCOPE_AGENT);
        while (__hip_atomic_load(bar, __ATOMIC_ACQUIRE, __HIP_MEMORY_SCOPE_AGENT) < target)
            __builtin_amdgcn_s_sleep(8);
    }
    __syncthreads();                       // rest of block waits on leader
}

// ---------------------------------------------------------------------------
__global__ void k_cvt(const float* __restrict__ src, bf16* __restrict__ dst, int n)
{
    int i = (blockIdx.x * blockDim.x + threadIdx.x) * 4;
    if (i < n) {
        float4 v = *reinterpret_cast<const float4*>(src + i);
        bf16x4 o;
        o[0] = (bf16)v.x; o[1] = (bf16)v.y; o[2] = (bf16)v.z; o[3] = (bf16)v.w;
        *reinterpret_cast<bf16x4*>(dst + i) = o;
    }
}

// ---------------------------------------------------------------------------
// Fused GRU phase: output tile 32x32 per WG (8 M-tiles x 32 N-tiles),
// 4-wave K-split over virtual K = [X(128) | E(1024)] = 1152, chunk 288/wave.
// Groups: 0=r, 1=z, 2=n_input(k<128), 3=n_hidden(k>=128). LDS reduce.
// ---------------------------------------------------------------------------
DEV void phase_gru(int wg, int lane, int wave, int lr, int lk,
                   const bf16* __restrict__ X, long xstride,
                   const bf16* __restrict__ Eb, const float* __restrict__ Ef,
                   const bf16* __restrict__ Wih, const bf16* __restrict__ Whh,
                   const float* __restrict__ bih, const float* __restrict__ bhh,
                   float* __restrict__ Eof, bf16* __restrict__ Eob,
                   float (&red)[4][32][33])
{
    const int mb = (wg >> 5) << 5;       // 0..224
    const int nb = (wg & 31) << 5;       // 0..992
    f32x4 acc[4][2][2] = {};
    const int k0 = wave * 288;
#pragma unroll 2
    for (int kk = 0; kk < 288; kk += 32) {
        const int k = k0 + kk;
        if (k < CIN) {
            bf16x8 a0 = ldfrag(X + (long)(mb + lr) * xstride + k + lk);
            bf16x8 a1 = ldfrag(X + (long)(mb + 16 + lr) * xstride + k + lk);
#pragma unroll
            for (int g = 0; g < 3; ++g) {
                const int grp = (g == 2) ? 2 : g;
                const bf16* wb = Wih + ((long)g * CH + nb + lr) * CIN + k + lk;
                bf16x8 b0 = ldfrag(wb), b1 = ldfrag(wb + 16 * CIN);
                acc[grp][0][0] = MFMA(a0, b0, acc[grp][0][0]);
                acc[grp][0][1] = MFMA(a0, b1, acc[grp][0][1]);
                acc[grp][1][0] = MFMA(a1, b0, acc[grp][1][0]);
                acc[grp][1][1] = MFMA(a1, b1, acc[grp][1][1]);
            }
        } else {
            const int ke = k - CIN;
            bf16x8 a0 = ldfrag(Eb + (long)(mb + lr) * CH + ke + lk);
            bf16x8 a1 = ldfrag(Eb + (long)(mb + 16 + lr) * CH + ke + lk);
#pragma unroll
            for (int g = 0; g < 3; ++g) {
                const int grp = (g == 2) ? 3 : g;
                const bf16* wb = Whh + ((long)g * CH + nb + lr) * CH + ke + lk;
                bf16x8 b0 = ldfrag(wb), b1 = ldfrag(wb + 16 * CH);
                acc[grp][0][0] = MFMA(a0, b0, acc[grp][0][0]);
                acc[grp][0][1] = MFMA(a0, b1, acc[grp][0][1]);
                acc[grp][1][0] = MFMA(a1, b0, acc[grp][1][0]);
                acc[grp][1][1] = MFMA(a1, b1, acc[grp][1][1]);
            }
        }
    }

    const int tid  = wave * 64 + lane;
    const int trow = tid >> 3;           // 0..31
    const int tcol = (tid & 7) << 2;     // 0,4,..,28
    float gval[4][4];
#pragma unroll
    for (int g = 0; g < 4; ++g) {
        __syncthreads();
#pragma unroll
        for (int mi = 0; mi < 2; ++mi)
#pragma unroll
            for (int ni = 0; ni < 2; ++ni)
#pragma unroll
                for (int i = 0; i < 4; ++i)
                    red[wave][mi * 16 + (lane >> 4) * 4 + i][ni * 16 + lr] = acc[g][mi][ni][i];
        __syncthreads();
#pragma unroll
        for (int j = 0; j < 4; ++j)
            gval[g][j] = red[0][trow][tcol + j] + red[1][trow][tcol + j]
                       + red[2][trow][tcol + j] + red[3][trow][tcol + j];
    }

    const int row = mb + trow;
    float4 ef4 = *reinterpret_cast<const float4*>(Ef + (long)row * CH + nb + tcol);
    float eo[4];
#pragma unroll
    for (int j = 0; j < 4; ++j) {
        const int col = nb + tcol + j;
        float gr = gval[0][j] + bih[col] + bhh[col];
        float gz = gval[1][j] + bih[CH + col] + bhh[CH + col];
        float gi = gval[2][j] + bih[2 * CH + col];
        float gh = gval[3][j] + bhh[2 * CH + col];
        float r = sigmoidf_(gr);
        float u = sigmoidf_(gz);
        float n = tanhf(gi + r * gh);
        float ep = (&ef4.x)[j];
        eo[j] = (1.0f - u) * n + u * ep;
    }
    *reinterpret_cast<float4*>(Eof + (long)row * CH + nb + tcol) =
        make_float4(eo[0], eo[1], eo[2], eo[3]);
    bf16x4 ob; ob[0] = (bf16)eo[0]; ob[1] = (bf16)eo[1]; ob[2] = (bf16)eo[2]; ob[3] = (bf16)eo[3];
    *reinterpret_cast<bf16x4*>(Eob + (long)row * CH + nb + tcol) = ob;
}

// ---------------------------------------------------------------------------
// Plain linear phase: Out(bf16 [256 x 1024]) = [A1|A2] @ Wm^T + bias
// 32x32 tile per WG, 4-wave K-split, LDS reduce.
// ---------------------------------------------------------------------------
DEV void phase_lin(int wg, int lane, int wave, int lr, int lk,
                   const bf16* __restrict__ A1, int K1, long a1s,
                   const bf16* __restrict__ A2, int K2,
                   const bf16* __restrict__ Wm, int ldw,
                   const float* __restrict__ bias, bf16* __restrict__ Ob,
                   float (&red)[4][32][33])
{
    const int mb = (wg >> 5) << 5;
    const int nb = (wg & 31) << 5;
    const int chunk = (K1 + K2) >> 2;
    f32x4 acc[2][2] = {};
    const int k0 = wave * chunk;
#pragma unroll 2
    for (int kk = 0; kk < chunk; kk += 32) {
        const int k = k0 + kk;
        bf16x8 a0, a1v;
        if (k < K1) {
            a0  = ldfrag(A1 + (long)(mb + lr) * a1s + k + lk);
            a1v = ldfrag(A1 + (long)(mb + 16 + lr) * a1s + k + lk);
        } else {
            const int ke = k - K1;
            a0  = ldfrag(A2 + (long)(mb + lr) * K2 + ke + lk);
            a1v = ldfrag(A2 + (long)(mb + 16 + lr) * K2 + ke + lk);
        }
        const bf16* wb = Wm + (long)(nb + lr) * ldw + k + lk;
        bf16x8 b0 = ldfrag(wb), b1 = ldfrag(wb + (long)16 * ldw);
        acc[0][0] = MFMA(a0, b0, acc[0][0]);
        acc[0][1] = MFMA(a0, b1, acc[0][1]);
        acc[1][0] = MFMA(a1v, b0, acc[1][0]);
        acc[1][1] = MFMA(a1v, b1, acc[1][1]);
    }

    const int tid  = wave * 64 + lane;
    const int trow = tid >> 3;
    const int tcol = (tid & 7) << 2;
    __syncthreads();
#pragma unroll
    for (int mi = 0; mi < 2; ++mi)
#pragma unroll
        for (int ni = 0; ni < 2; ++ni)
#pragma unroll
            for (int i = 0; i < 4; ++i)
                red[wave][mi * 16 + (lane >> 4) * 4 + i][ni * 16 + lr] = acc[mi][ni][i];
    __syncthreads();
    const int row = mb + trow;
    bf16x4 ob;
#pragma unroll
    for (int j = 0; j < 4; ++j) {
        float v = red[0][trow][tcol + j] + red[1][trow][tcol + j]
                + red[2][trow][tcol + j] + red[3][trow][tcol + j]
                + bias[nb + tcol + j];
        ob[j] = (bf16)v;
    }
    *reinterpret_cast<bf16x4*>(Ob + (long)row * CD + nb + tcol) = ob;
}

// ---------------------------------------------------------------------------
// Two-head tail phase (wg < 128 active): 16x16 tile, both heads, 4-wave
// K-split over K=1024 (chunk 256). MODE 0: qnet (mu, lv, z); MODE 1: pnet out.
// ---------------------------------------------------------------------------
template <int MODE>
DEV void phase_tail(const Prm& p, int t, int wg, int lane, int wave, int lr, int lk,
                    const bf16* __restrict__ A,
                    const bf16* __restrict__ Wa, const bf16* __restrict__ Wb,
                    const float* __restrict__ ba, const float* __restrict__ bb,
                    float (&red)[4][32][33])
{
    const int mb = (wg >> 3) << 4;   // 0..240
    const int nb = (wg & 7) << 4;    // 0..112
    f32x4 am = {}, as = {};
    const int k0 = wave * 256;
#pragma unroll 2
    for (int kk = 0; kk < 256; kk += 32) {
        const int k = k0 + kk;
        bf16x8 a  = ldfrag(A + (long)(mb + lr) * CD + k + lk);
        bf16x8 bm = ldfrag(Wa + (long)(nb + lr) * CD + k + lk);
        bf16x8 bs = ldfrag(Wb + (long)(nb + lr) * CD + k + lk);
        am = MFMA(a, bm, am);
        as = MFMA(a, bs, as);
    }
    const int tid  = wave * 64 + lane;
    const int trow = tid >> 4, tcol = tid & 15;
    __syncthreads();
#pragma unroll
    for (int i = 0; i < 4; ++i) red[wave][(lane >> 4) * 4 + i][lr] = am[i];
    __syncthreads();
    float vm = red[0][trow][tcol] + red[1][trow][tcol] + red[2][trow][tcol] + red[3][trow][tcol];
    __syncthreads();
#pragma unroll
    for (int i = 0; i < 4; ++i) red[wave][(lane >> 4) * 4 + i][lr] = as[i];
    __syncthreads();
    float vs = red[0][trow][tcol] + red[1][trow][tcol] + red[2][trow][tcol] + red[3][trow][tcol];

    const int row = mb + trow, col = nb + tcol;
    if constexpr (MODE == 0) {
        float mu = vm + ba[col];
        float lv = softplusf_(vs + bb[col]);
        float e  = p.eps_q[(long)row * CW * CZ + (long)t * CZ + col];
        float z  = mu + expf(0.5f * lv) * e;
        p.out_mu[(long)row * CW * CZ + (long)t * CZ + col] = mu;
        p.out_lv[(long)row * CW * CZ + (long)t * CZ + col] = lv;
        p.ztmp_f[(long)row * CZ + col] = z;
    } else {
        float m  = vm + ba[col];
        float sg = softplusf_(vs + bb[col]);
        float e  = p.eps_p[(long)row * CW * COUT + (long)t * COUT + col];
        p.out_o[(long)row * CW * COUT + (long)t * COUT + col] = m + sg * e;
    }
}

// ---------------------------------------------------------------------------
// Planar flows + LGSSM linear: one batch row per WG, fp32. Split-dot:
// thread (half=tid>>7, col=tid&127) sums 64 elems; LDS combine.
// ---------------------------------------------------------------------------
DEV void phase_flows(const Prm& p, int wg, int tid)
{
    __shared__ float zl[CZ];
    __shared__ float ps[2][CZ];
    const int row = wg;
    const int col = tid & 127, half = tid >> 7;

    if (tid < CZ) zl[tid] = p.ztmp_f[(long)row * CZ + tid];
    __syncthreads();

#pragma unroll 1
    for (int kf = 0; kf < 3; ++kf) {
        const float* wrow = p.Wp + ((long)kf * CZ + col) * CZ + half * 64;
        float s = 0.f;
#pragma unroll
        for (int j = 0; j < 64; j += 4) {
            float4 w = *reinterpret_cast<const float4*>(wrow + j);
            s += zl[half * 64 + j] * w.x + zl[half * 64 + j + 1] * w.y
               + zl[half * 64 + j + 2] * w.z + zl[half * 64 + j + 3] * w.w;
        }
        ps[half][col] = s;
        __syncthreads();
        if (tid < CZ) {
            float sf = ps[0][tid] + ps[1][tid] + p.bp[kf * CZ + tid];
            zl[tid] += p.up[kf] * tanhf(sf);
        }
        __syncthreads();
    }
    {
        const float* wrow = p.Wlg + (long)col * CZ + half * 64;
        float s = 0.f;
#pragma unroll
        for (int j = 0; j < 64; j += 4) {
            float4 w = *reinterpret_cast<const float4*>(wrow + j);
            s += zl[half * 64 + j] * w.x + zl[half * 64 + j + 1] * w.y
               + zl[half * 64 + j + 2] * w.z + zl[half * 64 + j + 3] * w.w;
        }
        ps[half][col] = s;
        __syncthreads();
        if (tid < CZ) {
            float zt = ps[0][tid] + ps[1][tid] + p.blg[tid];
            p.zt_b[(long)row * CZ + tid]   = (bf16)zt;
            p.zprev_b[(long)row * CZ + tid] = (bf16)zl[tid];
        }
    }
}

// ---------------------------------------------------------------------------
// Mega kernel: the whole forward pass, 6 software grid barriers per timestep.
// ---------------------------------------------------------------------------
__launch_bounds__(256)
__global__ void mega(Prm p)
{
    __shared__ float red[4][32][33];
    const int wg   = blockIdx.x;
    const int tid  = threadIdx.x;
    const int lane = tid & 63;
    const int wave = tid >> 6;
    const int lr   = lane & 15;
    const int lk   = (lane >> 4) * 8;
    unsigned bt = 0;   // barrier target (leader-maintained)

#pragma unroll 1
    for (int t = 0; t < CW; ++t) {
        const bool ev = (t & 1) == 0;
        const float* ef_i = ev ? p.e_f0 : p.e_f1;
        float*       ef_o = ev ? p.e_f1 : p.e_f0;
        const bf16*  eb_i = ev ? p.e_b0 : p.e_b1;
        bf16*        eb_o = ev ? p.e_b1 : p.e_b0;
        const float* df_i = ev ? p.d_f0 : p.d_f1;
        float*       df_o = ev ? p.d_f1 : p.d_f0;
        const bf16*  db_i = ev ? p.d_b0 : p.d_b1;
        bf16*        db_o = ev ? p.d_b1 : p.d_b0;

        // Q1: GRU encoder
        phase_gru(wg, lane, wave, lr, lk,
                  p.x_b + (long)t * CIN, (long)CW * CIN,
                  eb_i, ef_i, p.Wih_qb, p.Whh_qb, p.bih_q, p.bhh_q,
                  ef_o, eb_o, red);
        gbar(p.bar, bt);
        // Q2: d = [z_prev | e] @ Wd_q^T + bd_q
        phase_lin(wg, lane, wave, lr, lk,
                  p.zprev_b, CZ, (long)CZ,
                  eb_o, CH, p.Wd_qb, CZ + CH, p.bd_q, p.dvec_b, red);
        gbar(p.bar, bt);
        // Q3: mu / lv / reparam z
        if (wg < 128)
            phase_tail<0>(p, t, wg, lane, wave, lr, lk,
                          p.dvec_b, p.Wmu_qb, p.Wsg_qb, p.bmu_q, p.bsig_q, red);
        gbar(p.bar, bt);
        // Q4: planar flows + LGSSM linear
        phase_flows(p, wg, tid);
        gbar(p.bar, bt);
        // P1: GRU decoder (input zt)
        phase_gru(wg, lane, wave, lr, lk,
                  p.zt_b, (long)CZ,
                  db_i, df_i, p.Wih_pb, p.Whh_pb, p.bih_p, p.bhh_p,
                  df_o, db_o, red);
        gbar(p.bar, bt);
        // P2: dd = d @ Wd_p^T + bd_p
        phase_lin(wg, lane, wave, lr, lk,
                  nullptr, 0, 0,
                  db_o, CH, p.Wd_pb, CH, p.bd_p, p.ddvec_b, red);
        gbar(p.bar, bt);
        // P3: output head (no trailing barrier: writes only out_o; next
        // iteration's phases touch disjoint buffers until 2 barriers later)
        if (wg < 128)
            phase_tail<1>(p, t, wg, lane, wave, lr, lk,
                          p.ddvec_b, p.Wmu_pb, p.Wsg_pb, p.bmu_p, p.bsig_p, red);
    }
}

// ---------------------------------------------------------------------------
// Host driver
// ---------------------------------------------------------------------------
extern "C" void kernel_launch(void* const* d_in, const int* in_sizes, int n_in,
                              void* d_out, int out_size, void* d_ws, size_t ws_size,
                              hipStream_t stream)
{
    Prm p;
    p.x      = (const float*)d_in[0];
    p.eps_q  = (const float*)d_in[1];
    p.eps_p  = (const float*)d_in[2];
    const float* Wih_q  = (const float*)d_in[3];
    const float* Whh_q  = (const float*)d_in[4];
    p.bih_q  = (const float*)d_in[5];
    p.bhh_q  = (const float*)d_in[6];
    const float* Wd_q   = (const float*)d_in[7];
    p.bd_q   = (const float*)d_in[8];
    const float* Wmu_q  = (const float*)d_in[9];
    p.bmu_q  = (const float*)d_in[10];
    const float* Wsig_q = (const float*)d_in[11];
    p.bsig_q = (const float*)d_in[12];
    p.Wp     = (const float*)d_in[13];
    p.bp     = (const float*)d_in[14];
    p.up     = (const float*)d_in[15];
    p.Wlg    = (const float*)d_in[16];
    p.blg    = (const float*)d_in[17];
    const float* Wih_p  = (const float*)d_in[18];
    const float* Whh_p  = (const float*)d_in[19];
    p.bih_p  = (const float*)d_in[20];
    p.bhh_p  = (const float*)d_in[21];
    const float* Wd_p   = (const float*)d_in[22];
    p.bd_p   = (const float*)d_in[23];
    const float* Wmu_p  = (const float*)d_in[24];
    p.bmu_p  = (const float*)d_in[25];
    const float* Wsig_p = (const float*)d_in[26];
    p.bsig_p = (const float*)d_in[27];

    p.out_o  = (float*)d_out;
    p.out_mu = p.out_o + (size_t)CB * CW * COUT;
    p.out_lv = p.out_mu + (size_t)CB * CW * CZ;

    char* wp_ = (char*)d_ws;
    auto carve = [&](size_t bytes) -> void* {
        void* q = (void*)wp_;
        wp_ += (bytes + 255) & ~(size_t)255;
        return q;
    };
    p.e_f0 = (float*)carve((size_t)CB * CH * 4);
    p.e_f1 = (float*)carve((size_t)CB * CH * 4);
    p.e_b0 = (bf16*)carve((size_t)CB * CH * 2);
    p.e_b1 = (bf16*)carve((size_t)CB * CH * 2);
    p.d_f0 = (float*)carve((size_t)CB * CH * 4);
    p.d_f1 = (float*)carve((size_t)CB * CH * 4);
    p.d_b0 = (bf16*)carve((size_t)CB * CH * 2);
    p.d_b1 = (bf16*)carve((size_t)CB * CH * 2);
    p.zprev_b = (bf16*)carve((size_t)CB * CZ * 2);
    p.zt_b    = (bf16*)carve((size_t)CB * CZ * 2);
    p.ztmp_f  = (float*)carve((size_t)CB * CZ * 4);
    p.dvec_b  = (bf16*)carve((size_t)CB * CD * 2);
    p.ddvec_b = (bf16*)carve((size_t)CB * CD * 2);
    p.bar     = (unsigned*)carve(256);
    bf16* x_b    = (bf16*)carve((size_t)CB * CW * CIN * 2);
    bf16* Wih_qb = (bf16*)carve((size_t)3 * CH * CIN * 2);
    bf16* Whh_qb = (bf16*)carve((size_t)3 * CH * CH * 2);
    bf16* Wd_qb  = (bf16*)carve((size_t)CD * (CZ + CH) * 2);
    bf16* Wmu_qb = (bf16*)carve((size_t)CZ * CD * 2);
    bf16* Wsg_qb = (bf16*)carve((size_t)CZ * CD * 2);
    bf16* Wih_pb = (bf16*)carve((size_t)3 * CH * CZ * 2);
    bf16* Whh_pb = (bf16*)carve((size_t)3 * CH * CH * 2);
    bf16* Wd_pb  = (bf16*)carve((size_t)CD * CH * 2);
    bf16* Wmu_pb = (bf16*)carve((size_t)COUT * CD * 2);
    bf16* Wsg_pb = (bf16*)carve((size_t)COUT * CD * 2);
    p.x_b = x_b;       p.Wih_qb = Wih_qb; p.Whh_qb = Whh_qb;
    p.Wd_qb = Wd_qb;   p.Wmu_qb = Wmu_qb; p.Wsg_qb = Wsg_qb;
    p.Wih_pb = Wih_pb; p.Whh_pb = Whh_pb; p.Wd_pb = Wd_pb;
    p.Wmu_pb = Wmu_pb; p.Wsg_pb = Wsg_pb;

    hipMemsetAsync(p.e_f0, 0, (size_t)CB * CH * 4, stream);
    hipMemsetAsync(p.e_b0, 0, (size_t)CB * CH * 2, stream);
    hipMemsetAsync(p.d_f0, 0, (size_t)CB * CH * 4, stream);
    hipMemsetAsync(p.d_b0, 0, (size_t)CB * CH * 2, stream);
    hipMemsetAsync(p.zprev_b, 0, (size_t)CB * CZ * 2, stream);
    hipMemsetAsync(p.bar, 0, 256, stream);

    auto cvt = [&](const float* s, bf16* d, size_t n) {
        k_cvt<<<dim3((unsigned)((n / 4 + 255) / 256)), dim3(256), 0, stream>>>(s, d, (int)n);
    };
    cvt(p.x,    x_b,    (size_t)CB * CW * CIN);
    cvt(Wih_q,  Wih_qb, (size_t)3 * CH * CIN);
    cvt(Whh_q,  Whh_qb, (size_t)3 * CH * CH);
    cvt(Wd_q,   Wd_qb,  (size_t)CD * (CZ + CH));
    cvt(Wmu_q,  Wmu_qb, (size_t)CZ * CD);
    cvt(Wsig_q, Wsg_qb, (size_t)CZ * CD);
    cvt(Wih_p,  Wih_pb, (size_t)3 * CH * CZ);
    cvt(Whh_p,  Whh_pb, (size_t)3 * CH * CH);
    cvt(Wd_p,   Wd_pb,  (size_t)CD * CH);
    cvt(Wmu_p,  Wmu_pb, (size_t)COUT * CD);
    cvt(Wsig_p, Wsg_pb, (size_t)COUT * CD);

    mega<<<dim3(NWG), dim3(256), 0, stream>>>(p);
}

// Round 5
// 12846.664 us; speedup vs baseline: 1.9276x; 1.8874x over previous
//
#include <hip/hip_runtime.h>

// ---------------------------------------------------------------------------
// OmniAnomaly forward, persistent mega-kernel, FENCE-FREE grid sync.
// Round 5: cross-WG activations = relaxed agent-scope atomics (coherent via
// MALL, no L2 invalidates) -> weights stay L2-resident. Barrier = per-WG flag
// array, vmcnt-drain + relaxed atomics, no fences.
// B=256, W=128, IN=128, H=1024, Z=128, D=1024, OUT=128, K=3 flows
// ---------------------------------------------------------------------------

typedef __bf16 bf16;
typedef __bf16 bf16x4 __attribute__((ext_vector_type(4)));
typedef __bf16 bf16x8 __attribute__((ext_vector_type(8)));
typedef float  f32x4  __attribute__((ext_vector_type(4)));
typedef unsigned long long u64;
typedef unsigned u32;

static constexpr int CB   = 256;
static constexpr int CW   = 128;
static constexpr int CIN  = 128;
static constexpr int CH   = 1024;
static constexpr int CZ   = 128;
static constexpr int CD   = 1024;
static constexpr int COUT = 128;
static constexpr int NWG  = 256;   // grid size == block size (each thread polls 1 flag)

#define DEV static __device__ __forceinline__

DEV float sigmoidf_(float x) { return 1.0f / (1.0f + expf(-x)); }
DEV float softplusf_(float x) { return x > 20.0f ? x : log1pf(expf(x)); }
DEV bf16x8 ldfrag(const bf16* p) { return *reinterpret_cast<const bf16x8*>(p); }

#define MFMA(a, b, c) __builtin_amdgcn_mfma_f32_16x16x32_bf16((a), (b), (c), 0, 0, 0)

// ---- relaxed agent-scope (cross-XCD coherent, fence-free) access helpers ----
DEV u64 lda8(const void* p) {
    return __hip_atomic_load((const u64*)p, __ATOMIC_RELAXED, __HIP_MEMORY_SCOPE_AGENT);
}
DEV void sta8(void* p, u64 v) {
    __hip_atomic_store((u64*)p, v, __ATOMIC_RELAXED, __HIP_MEMORY_SCOPE_AGENT);
}
DEV u32 lda4(const void* p) {
    return __hip_atomic_load((const u32*)p, __ATOMIC_RELAXED, __HIP_MEMORY_SCOPE_AGENT);
}
DEV void sta4(void* p, u32 v) {
    __hip_atomic_store((u32*)p, v, __ATOMIC_RELAXED, __HIP_MEMORY_SCOPE_AGENT);
}
DEV bf16x8 ld_act16(const bf16* p) {
    union { u64 u[2]; bf16x8 v; } r;
    r.u[0] = lda8(p);
    r.u[1] = lda8((const char*)p + 8);
    return r.v;
}
DEV void st_actbf4(bf16* p, bf16x4 v) {
    union { bf16x4 b; u64 u; } r; r.b = v;
    sta8(p, r.u);
}

struct Prm {
    const float *x, *eps_q, *eps_p;
    const float *bih_q, *bhh_q, *bd_q, *bmu_q, *bsig_q;
    const float *Wp, *bp, *up, *Wlg, *blg;
    const float *bih_p, *bhh_p, *bd_p, *bmu_p, *bsig_p;
    const bf16 *x_b, *Wih_qb, *Whh_qb, *Wd_qb, *Wmu_qb, *Wsg_qb;
    const bf16 *Wih_pb, *Whh_pb, *Wd_pb, *Wmu_pb, *Wsg_pb;
    float *e_f0, *e_f1; bf16 *e_b0, *e_b1;
    float *d_f0, *d_f1; bf16 *d_b0, *d_b1;
    bf16 *zprev_b, *zt_b; float *ztmp_f;
    bf16 *dvec_b, *ddvec_b;
    u32 *bar;
    float *out_o, *out_mu, *out_lv;
};

// ---------------------------------------------------------------------------
// Fence-free grid barrier. Each WG publishes its progress (monotonic k) in its
// own flag; each of the 256 threads polls one WG's flag. vmcnt(0) drain before
// publishing guarantees this WG's agent-scope stores are globally visible.
// bar[] is memset to 0 at the start of each kernel_launch (graph-replayed).
// ---------------------------------------------------------------------------
DEV void gbar(u32* bar, u32 k)
{
    asm volatile("s_waitcnt vmcnt(0)" ::: "memory");   // per-wave: drain stores
    __syncthreads();                                   // whole WG drained
    if (threadIdx.x == 0)
        __hip_atomic_store(&bar[blockIdx.x], k, __ATOMIC_RELAXED, __HIP_MEMORY_SCOPE_AGENT);
    u32 v;
    do {
        v = __hip_atomic_load(&bar[threadIdx.x], __ATOMIC_RELAXED, __HIP_MEMORY_SCOPE_AGENT);
        if (v >= k) break;
        __builtin_amdgcn_s_sleep(2);
    } while (true);
    __syncthreads();
}

// ---------------------------------------------------------------------------
__global__ void k_cvt(const float* __restrict__ src, bf16* __restrict__ dst, int n)
{
    int i = (blockIdx.x * blockDim.x + threadIdx.x) * 4;
    if (i < n) {
        float4 v = *reinterpret_cast<const float4*>(src + i);
        bf16x4 o;
        o[0] = (bf16)v.x; o[1] = (bf16)v.y; o[2] = (bf16)v.z; o[3] = (bf16)v.w;
        *reinterpret_cast<bf16x4*>(dst + i) = o;
    }
}

// ---------------------------------------------------------------------------
// Fused GRU phase: 32x32 output tile per WG (8 M-tiles x 32 N-tiles),
// 4-wave K-split over virtual K = [X(128) | E(1024)] = 1152 (288/wave).
// Weights: normal cached loads (L2-resident). Activations (X when xsc, Eb):
// agent-scope. Ef/Eof: same-WG-owned tile -> normal cached fp32.
// ---------------------------------------------------------------------------
DEV void phase_gru(int wg, int lane, int wave, int lr, int lk, int xsc,
                   const bf16* __restrict__ X, long xstride,
                   const bf16* __restrict__ Eb, const float* __restrict__ Ef,
                   const bf16* __restrict__ Wih, const bf16* __restrict__ Whh,
                   const float* __restrict__ bih, const float* __restrict__ bhh,
                   float* __restrict__ Eof, bf16* __restrict__ Eob,
                   float (&red)[4][32][33])
{
    const int mb = (wg >> 5) << 5;       // 0..224
    const int nb = (wg & 31) << 5;       // 0..992
    f32x4 acc[4][2][2] = {};
    const int k0 = wave * 288;
#pragma unroll 2
    for (int kk = 0; kk < 288; kk += 32) {
        const int k = k0 + kk;
        if (k < CIN) {
            bf16x8 a0, a1;
            if (xsc) {
                a0 = ld_act16(X + (long)(mb + lr) * xstride + k + lk);
                a1 = ld_act16(X + (long)(mb + 16 + lr) * xstride + k + lk);
            } else {
                a0 = ldfrag(X + (long)(mb + lr) * xstride + k + lk);
                a1 = ldfrag(X + (long)(mb + 16 + lr) * xstride + k + lk);
            }
#pragma unroll
            for (int g = 0; g < 3; ++g) {
                const int grp = (g == 2) ? 2 : g;
                const bf16* wb = Wih + ((long)g * CH + nb + lr) * CIN + k + lk;
                bf16x8 b0 = ldfrag(wb), b1 = ldfrag(wb + 16 * CIN);
                acc[grp][0][0] = MFMA(a0, b0, acc[grp][0][0]);
                acc[grp][0][1] = MFMA(a0, b1, acc[grp][0][1]);
                acc[grp][1][0] = MFMA(a1, b0, acc[grp][1][0]);
                acc[grp][1][1] = MFMA(a1, b1, acc[grp][1][1]);
            }
        } else {
            const int ke = k - CIN;
            bf16x8 a0 = ld_act16(Eb + (long)(mb + lr) * CH + ke + lk);
            bf16x8 a1 = ld_act16(Eb + (long)(mb + 16 + lr) * CH + ke + lk);
#pragma unroll
            for (int g = 0; g < 3; ++g) {
                const int grp = (g == 2) ? 3 : g;
                const bf16* wb = Whh + ((long)g * CH + nb + lr) * CH + ke + lk;
                bf16x8 b0 = ldfrag(wb), b1 = ldfrag(wb + 16 * CH);
                acc[grp][0][0] = MFMA(a0, b0, acc[grp][0][0]);
                acc[grp][0][1] = MFMA(a0, b1, acc[grp][0][1]);
                acc[grp][1][0] = MFMA(a1, b0, acc[grp][1][0]);
                acc[grp][1][1] = MFMA(a1, b1, acc[grp][1][1]);
            }
        }
    }

    const int tid  = wave * 64 + lane;
    const int trow = tid >> 3;           // 0..31
    const int tcol = (tid & 7) << 2;     // 0,4,..,28
    float gval[4][4];
#pragma unroll
    for (int g = 0; g < 4; ++g) {
        __syncthreads();
#pragma unroll
        for (int mi = 0; mi < 2; ++mi)
#pragma unroll
            for (int ni = 0; ni < 2; ++ni)
#pragma unroll
                for (int i = 0; i < 4; ++i)
                    red[wave][mi * 16 + (lane >> 4) * 4 + i][ni * 16 + lr] = acc[g][mi][ni][i];
        __syncthreads();
#pragma unroll
        for (int j = 0; j < 4; ++j)
            gval[g][j] = red[0][trow][tcol + j] + red[1][trow][tcol + j]
                       + red[2][trow][tcol + j] + red[3][trow][tcol + j];
    }

    const int row = mb + trow;
    float4 ef4 = *reinterpret_cast<const float4*>(Ef + (long)row * CH + nb + tcol);
    float eo[4];
#pragma unroll
    for (int j = 0; j < 4; ++j) {
        const int col = nb + tcol + j;
        float gr = gval[0][j] + bih[col] + bhh[col];
        float gz = gval[1][j] + bih[CH + col] + bhh[CH + col];
        float gi = gval[2][j] + bih[2 * CH + col];
        float gh = gval[3][j] + bhh[2 * CH + col];
        float r = sigmoidf_(gr);
        float u = sigmoidf_(gz);
        float n = tanhf(gi + r * gh);
        float ep = (&ef4.x)[j];
        eo[j] = (1.0f - u) * n + u * ep;
    }
    *reinterpret_cast<float4*>(Eof + (long)row * CH + nb + tcol) =
        make_float4(eo[0], eo[1], eo[2], eo[3]);
    bf16x4 ob; ob[0] = (bf16)eo[0]; ob[1] = (bf16)eo[1]; ob[2] = (bf16)eo[2]; ob[3] = (bf16)eo[3];
    st_actbf4(Eob + (long)row * CH + nb + tcol, ob);
}

// ---------------------------------------------------------------------------
// Plain linear phase: Out(bf16 [256 x 1024]) = [A1|A2] @ Wm^T + bias
// 32x32 tile per WG, 4-wave K-split, LDS reduce. A: agent-scope loads.
// ---------------------------------------------------------------------------
DEV void phase_lin(int wg, int lane, int wave, int lr, int lk,
                   const bf16* __restrict__ A1, int K1, long a1s,
                   const bf16* __restrict__ A2, int K2,
                   const bf16* __restrict__ Wm, int ldw,
                   const float* __restrict__ bias, bf16* __restrict__ Ob,
                   float (&red)[4][32][33])
{
    const int mb = (wg >> 5) << 5;
    const int nb = (wg & 31) << 5;
    const int chunk = (K1 + K2) >> 2;
    f32x4 acc[2][2] = {};
    const int k0 = wave * chunk;
#pragma unroll 2
    for (int kk = 0; kk < chunk; kk += 32) {
        const int k = k0 + kk;
        bf16x8 a0, a1v;
        if (k < K1) {
            a0  = ld_act16(A1 + (long)(mb + lr) * a1s + k + lk);
            a1v = ld_act16(A1 + (long)(mb + 16 + lr) * a1s + k + lk);
        } else {
            const int ke = k - K1;
            a0  = ld_act16(A2 + (long)(mb + lr) * K2 + ke + lk);
            a1v = ld_act16(A2 + (long)(mb + 16 + lr) * K2 + ke + lk);
        }
        const bf16* wb = Wm + (long)(nb + lr) * ldw + k + lk;
        bf16x8 b0 = ldfrag(wb), b1 = ldfrag(wb + (long)16 * ldw);
        acc[0][0] = MFMA(a0, b0, acc[0][0]);
        acc[0][1] = MFMA(a0, b1, acc[0][1]);
        acc[1][0] = MFMA(a1v, b0, acc[1][0]);
        acc[1][1] = MFMA(a1v, b1, acc[1][1]);
    }

    const int tid  = wave * 64 + lane;
    const int trow = tid >> 3;
    const int tcol = (tid & 7) << 2;
    __syncthreads();
#pragma unroll
    for (int mi = 0; mi < 2; ++mi)
#pragma unroll
        for (int ni = 0; ni < 2; ++ni)
#pragma unroll
            for (int i = 0; i < 4; ++i)
                red[wave][mi * 16 + (lane >> 4) * 4 + i][ni * 16 + lr] = acc[mi][ni][i];
    __syncthreads();
    const int row = mb + trow;
    bf16x4 ob;
#pragma unroll
    for (int j = 0; j < 4; ++j) {
        float v = red[0][trow][tcol + j] + red[1][trow][tcol + j]
                + red[2][trow][tcol + j] + red[3][trow][tcol + j]
                + bias[nb + tcol + j];
        ob[j] = (bf16)v;
    }
    st_actbf4(Ob + (long)row * CD + nb + tcol, ob);
}

// ---------------------------------------------------------------------------
// Two-head tail phase (wg < 128 active): 16x16 tile, both heads, 4-wave
// K-split over K=1024. MODE 0: qnet (mu, lv, z); MODE 1: pnet out.
// ---------------------------------------------------------------------------
template <int MODE>
DEV void phase_tail(const Prm& p, int t, int wg, int lane, int wave, int lr, int lk,
                    const bf16* __restrict__ A,
                    const bf16* __restrict__ Wa, const bf16* __restrict__ Wb,
                    const float* __restrict__ ba, const float* __restrict__ bb,
                    float (&red)[4][32][33])
{
    const int mb = (wg >> 3) << 4;   // 0..240
    const int nb = (wg & 7) << 4;    // 0..112
    f32x4 am = {}, as = {};
    const int k0 = wave * 256;
#pragma unroll 2
    for (int kk = 0; kk < 256; kk += 32) {
        const int k = k0 + kk;
        bf16x8 a  = ld_act16(A + (long)(mb + lr) * CD + k + lk);
        bf16x8 bm = ldfrag(Wa + (long)(nb + lr) * CD + k + lk);
        bf16x8 bs = ldfrag(Wb + (long)(nb + lr) * CD + k + lk);
        am = MFMA(a, bm, am);
        as = MFMA(a, bs, as);
    }
    const int tid  = wave * 64 + lane;
    const int trow = tid >> 4, tcol = tid & 15;
    __syncthreads();
#pragma unroll
    for (int i = 0; i < 4; ++i) red[wave][(lane >> 4) * 4 + i][lr] = am[i];
    __syncthreads();
    float vm = red[0][trow][tcol] + red[1][trow][tcol] + red[2][trow][tcol] + red[3][trow][tcol];
    __syncthreads();
#pragma unroll
    for (int i = 0; i < 4; ++i) red[wave][(lane >> 4) * 4 + i][lr] = as[i];
    __syncthreads();
    float vs = red[0][trow][tcol] + red[1][trow][tcol] + red[2][trow][tcol] + red[3][trow][tcol];

    const int row = mb + trow, col = nb + tcol;
    if constexpr (MODE == 0) {
        float mu = vm + ba[col];
        float lv = softplusf_(vs + bb[col]);
        float e  = p.eps_q[(long)row * CW * CZ + (long)t * CZ + col];
        float z  = mu + expf(0.5f * lv) * e;
        p.out_mu[(long)row * CW * CZ + (long)t * CZ + col] = mu;
        p.out_lv[(long)row * CW * CZ + (long)t * CZ + col] = lv;
        sta4(p.ztmp_f + (long)row * CZ + col, __float_as_uint(z));
    } else {
        float m  = vm + ba[col];
        float sg = softplusf_(vs + bb[col]);
        float e  = p.eps_p[(long)row * CW * COUT + (long)t * COUT + col];
        p.out_o[(long)row * CW * COUT + (long)t * COUT + col] = m + sg * e;
    }
}

// ---------------------------------------------------------------------------
// Planar flows + LGSSM linear: one batch row per WG, fp32.
// ---------------------------------------------------------------------------
DEV void phase_flows(const Prm& p, int wg, int tid)
{
    __shared__ float zl[CZ];
    __shared__ float ps[2][CZ];
    const int row = wg;
    const int col = tid & 127, half = tid >> 7;

    if (tid < CZ) zl[tid] = __uint_as_float(lda4(p.ztmp_f + (long)row * CZ + tid));
    __syncthreads();

#pragma unroll 1
    for (int kf = 0; kf < 3; ++kf) {
        const float* wrow = p.Wp + ((long)kf * CZ + col) * CZ + half * 64;
        float s = 0.f;
#pragma unroll
        for (int j = 0; j < 64; j += 4) {
            float4 w = *reinterpret_cast<const float4*>(wrow + j);
            s += zl[half * 64 + j] * w.x + zl[half * 64 + j + 1] * w.y
               + zl[half * 64 + j + 2] * w.z + zl[half * 64 + j + 3] * w.w;
        }
        ps[half][col] = s;
        __syncthreads();
        if (tid < CZ) {
            float sf = ps[0][tid] + ps[1][tid] + p.bp[kf * CZ + tid];
            zl[tid] += p.up[kf] * tanhf(sf);
        }
        __syncthreads();
    }
    {
        const float* wrow = p.Wlg + (long)col * CZ + half * 64;
        float s = 0.f;
#pragma unroll
        for (int j = 0; j < 64; j += 4) {
            float4 w = *reinterpret_cast<const float4*>(wrow + j);
            s += zl[half * 64 + j] * w.x + zl[half * 64 + j + 1] * w.y
               + zl[half * 64 + j + 2] * w.z + zl[half * 64 + j + 3] * w.w;
        }
        ps[half][col] = s;
        __syncthreads();
        if (tid < 64) {
            const int c0 = tid * 2;
            float zt0 = ps[0][c0] + ps[1][c0] + p.blg[c0];
            float zt1 = ps[0][c0 + 1] + ps[1][c0 + 1] + p.blg[c0 + 1];
            union { bf16 b[2]; u32 u; } za, zb;
            za.b[0] = (bf16)zt0;      za.b[1] = (bf16)zt1;
            zb.b[0] = (bf16)zl[c0];   zb.b[1] = (bf16)zl[c0 + 1];
            sta4(p.zt_b + (long)row * CZ + c0, za.u);
            sta4(p.zprev_b + (long)row * CZ + c0, zb.u);
        }
    }
}

// ---------------------------------------------------------------------------
// Mega kernel: whole forward pass, 6 fence-free grid barriers per timestep.
// ---------------------------------------------------------------------------
__launch_bounds__(256)
__global__ void mega(Prm p)
{
    __shared__ float red[4][32][33];
    const int wg   = blockIdx.x;
    const int tid  = threadIdx.x;
    const int lane = tid & 63;
    const int wave = tid >> 6;
    const int lr   = lane & 15;
    const int lk   = (lane >> 4) * 8;
    u32 bk = 0;   // barrier index (uniform across all WGs)

#pragma unroll 1
    for (int t = 0; t < CW; ++t) {
        const bool ev = (t & 1) == 0;
        const float* ef_i = ev ? p.e_f0 : p.e_f1;
        float*       ef_o = ev ? p.e_f1 : p.e_f0;
        const bf16*  eb_i = ev ? p.e_b0 : p.e_b1;
        bf16*        eb_o = ev ? p.e_b1 : p.e_b0;
        const float* df_i = ev ? p.d_f0 : p.d_f1;
        float*       df_o = ev ? p.d_f1 : p.d_f0;
        const bf16*  db_i = ev ? p.d_b0 : p.d_b1;
        bf16*        db_o = ev ? p.d_b1 : p.d_b0;

        // Q1: GRU encoder
        phase_gru(wg, lane, wave, lr, lk, /*xsc=*/0,
                  p.x_b + (long)t * CIN, (long)CW * CIN,
                  eb_i, ef_i, p.Wih_qb, p.Whh_qb, p.bih_q, p.bhh_q,
                  ef_o, eb_o, red);
        gbar(p.bar, ++bk);
        // Q2: d = [z_prev | e] @ Wd_q^T + bd_q
        phase_lin(wg, lane, wave, lr, lk,
                  p.zprev_b, CZ, (long)CZ,
                  eb_o, CH, p.Wd_qb, CZ + CH, p.bd_q, p.dvec_b, red);
        gbar(p.bar, ++bk);
        // Q3: mu / lv / reparam z
        if (wg < 128)
            phase_tail<0>(p, t, wg, lane, wave, lr, lk,
                          p.dvec_b, p.Wmu_qb, p.Wsg_qb, p.bmu_q, p.bsig_q, red);
        gbar(p.bar, ++bk);
        // Q4: planar flows + LGSSM linear
        phase_flows(p, wg, tid);
        gbar(p.bar, ++bk);
        // P1: GRU decoder (input zt, agent-scope)
        phase_gru(wg, lane, wave, lr, lk, /*xsc=*/1,
                  p.zt_b, (long)CZ,
                  db_i, df_i, p.Wih_pb, p.Whh_pb, p.bih_p, p.bhh_p,
                  df_o, db_o, red);
        gbar(p.bar, ++bk);
        // P2: dd = d @ Wd_p^T + bd_p
        phase_lin(wg, lane, wave, lr, lk,
                  nullptr, 0, 0,
                  db_o, CH, p.Wd_pb, CH, p.bd_p, p.ddvec_b, red);
        gbar(p.bar, ++bk);
        // P3: output head (no trailing barrier: writes only out_o; next
        // iteration's phases touch disjoint buffers until 2 barriers later)
        if (wg < 128)
            phase_tail<1>(p, t, wg, lane, wave, lr, lk,
                          p.ddvec_b, p.Wmu_pb, p.Wsg_pb, p.bmu_p, p.bsig_p, red);
    }
}

// ---------------------------------------------------------------------------
// Host driver
// ---------------------------------------------------------------------------
extern "C" void kernel_launch(void* const* d_in, const int* in_sizes, int n_in,
                              void* d_out, int out_size, void* d_ws, size_t ws_size,
                              hipStream_t stream)
{
    Prm p;
    p.x      = (const float*)d_in[0];
    p.eps_q  = (const float*)d_in[1];
    p.eps_p  = (const float*)d_in[2];
    const float* Wih_q  = (const float*)d_in[3];
    const float* Whh_q  = (const float*)d_in[4];
    p.bih_q  = (const float*)d_in[5];
    p.bhh_q  = (const float*)d_in[6];
    const float* Wd_q   = (const float*)d_in[7];
    p.bd_q   = (const float*)d_in[8];
    const float* Wmu_q  = (const float*)d_in[9];
    p.bmu_q  = (const float*)d_in[10];
    const float* Wsig_q = (const float*)d_in[11];
    p.bsig_q = (const float*)d_in[12];
    p.Wp     = (const float*)d_in[13];
    p.bp     = (const float*)d_in[14];
    p.up     = (const float*)d_in[15];
    p.Wlg    = (const float*)d_in[16];
    p.blg    = (const float*)d_in[17];
    const float* Wih_p  = (const float*)d_in[18];
    const float* Whh_p  = (const float*)d_in[19];
    p.bih_p  = (const float*)d_in[20];
    p.bhh_p  = (const float*)d_in[21];
    const float* Wd_p   = (const float*)d_in[22];
    p.bd_p   = (const float*)d_in[23];
    const float* Wmu_p  = (const float*)d_in[24];
    p.bmu_p  = (const float*)d_in[25];
    const float* Wsig_p = (const float*)d_in[26];
    p.bsig_p = (const float*)d_in[27];

    p.out_o  = (float*)d_out;
    p.out_mu = p.out_o + (size_t)CB * CW * COUT;
    p.out_lv = p.out_mu + (size_t)CB * CW * CZ;

    char* wp_ = (char*)d_ws;
    auto carve = [&](size_t bytes) -> void* {
        void* q = (void*)wp_;
        wp_ += (bytes + 255) & ~(size_t)255;
        return q;
    };
    p.e_f0 = (float*)carve((size_t)CB * CH * 4);
    p.e_f1 = (float*)carve((size_t)CB * CH * 4);
    p.e_b0 = (bf16*)carve((size_t)CB * CH * 2);
    p.e_b1 = (bf16*)carve((size_t)CB * CH * 2);
    p.d_f0 = (float*)carve((size_t)CB * CH * 4);
    p.d_f1 = (float*)carve((size_t)CB * CH * 4);
    p.d_b0 = (bf16*)carve((size_t)CB * CH * 2);
    p.d_b1 = (bf16*)carve((size_t)CB * CH * 2);
    p.zprev_b = (bf16*)carve((size_t)CB * CZ * 2);
    p.zt_b    = (bf16*)carve((size_t)CB * CZ * 2);
    p.ztmp_f  = (float*)carve((size_t)CB * CZ * 4);
    p.dvec_b  = (bf16*)carve((size_t)CB * CD * 2);
    p.ddvec_b = (bf16*)carve((size_t)CB * CD * 2);
    p.bar     = (u32*)carve((size_t)NWG * 4);
    bf16* x_b    = (bf16*)carve((size_t)CB * CW * CIN * 2);
    bf16* Wih_qb = (bf16*)carve((size_t)3 * CH * CIN * 2);
    bf16* Whh_qb = (bf16*)carve((size_t)3 * CH * CH * 2);
    bf16* Wd_qb  = (bf16*)carve((size_t)CD * (CZ + CH) * 2);
    bf16* Wmu_qb = (bf16*)carve((size_t)CZ * CD * 2);
    bf16* Wsg_qb = (bf16*)carve((size_t)CZ * CD * 2);
    bf16* Wih_pb = (bf16*)carve((size_t)3 * CH * CZ * 2);
    bf16* Whh_pb = (bf16*)carve((size_t)3 * CH * CH * 2);
    bf16* Wd_pb  = (bf16*)carve((size_t)CD * CH * 2);
    bf16* Wmu_pb = (bf16*)carve((size_t)COUT * CD * 2);
    bf16* Wsg_pb = (bf16*)carve((size_t)COUT * CD * 2);
    p.x_b = x_b;       p.Wih_qb = Wih_qb; p.Whh_qb = Whh_qb;
    p.Wd_qb = Wd_qb;   p.Wmu_qb = Wmu_qb; p.Wsg_qb = Wsg_qb;
    p.Wih_pb = Wih_pb; p.Whh_pb = Whh_pb; p.Wd_pb = Wd_pb;
    p.Wmu_pb = Wmu_pb; p.Wsg_pb = Wsg_pb;

    hipMemsetAsync(p.e_f0, 0, (size_t)CB * CH * 4, stream);
    hipMemsetAsync(p.e_b0, 0, (size_t)CB * CH * 2, stream);
    hipMemsetAsync(p.d_f0, 0, (size_t)CB * CH * 4, stream);
    hipMemsetAsync(p.d_b0, 0, (size_t)CB * CH * 2, stream);
    hipMemsetAsync(p.zprev_b, 0, (size_t)CB * CZ * 2, stream);
    hipMemsetAsync(p.bar, 0, (size_t)NWG * 4, stream);

    auto cvt = [&](const float* s, bf16* d, size_t n) {
        k_cvt<<<dim3((unsigned)((n / 4 + 255) / 256)), dim3(256), 0, stream>>>(s, d, (int)n);
    };
    cvt(p.x,    x_b,    (size_t)CB * CW * CIN);
    cvt(Wih_q,  Wih_qb, (size_t)3 * CH * CIN);
    cvt(Whh_q,  Whh_qb, (size_t)3 * CH * CH);
    cvt(Wd_q,   Wd_qb,  (size_t)CD * (CZ + CH));
    cvt(Wmu_q,  Wmu_qb, (size_t)CZ * CD);
    cvt(Wsig_q, Wsg_qb, (size_t)CZ * CD);
    cvt(Wih_p,  Wih_pb, (size_t)3 * CH * CZ);
    cvt(Whh_p,  Whh_pb, (size_t)3 * CH * CH);
    cvt(Wd_p,   Wd_pb,  (size_t)CD * CH);
    cvt(Wmu_p,  Wmu_pb, (size_t)COUT * CD);
    cvt(Wsig_p, Wsg_pb, (size_t)COUT * CD);

    mega<<<dim3(NWG), dim3(256), 0, stream>>>(p);
}

// Round 6
// 10196.989 us; speedup vs baseline: 2.4285x; 1.2598x over previous
//
#include <hip/hip_runtime.h>

// ---------------------------------------------------------------------------
// OmniAnomaly forward, round 6: weight-stationary persistent mega-kernel.
// WGs 0..127 = Qnet, WGs 128..255 = Pnet (software-pipelined via z-queue).
// Each WG keeps its GRU weight slice (Whh+Wih, 110.8 KB) in LDS for all 128
// timesteps. Cross-WG activations: relaxed agent-scope atomics (proven r4/r5).
// Per-half flag-array barriers (Q: 3/step, P: 2/step), fence-free.
// B=256, W=128, IN=128, H=1024, Z=128, D=1024, OUT=128, K=3 flows
// ---------------------------------------------------------------------------

typedef __bf16 bf16;
typedef __bf16 bf16x4 __attribute__((ext_vector_type(4)));
typedef __bf16 bf16x8 __attribute__((ext_vector_type(8)));
typedef float  f32x4  __attribute__((ext_vector_type(4)));
typedef unsigned long long u64;
typedef unsigned u32;

static constexpr int CB   = 256;
static constexpr int CW   = 128;
static constexpr int CIN  = 128;
static constexpr int CH   = 1024;
static constexpr int CZ   = 128;
static constexpr int CD   = 1024;
static constexpr int COUT = 128;

// LDS weight slice: 16 rows x (3*1024 Whh | 3*128 Wih) elems, padded pitch.
static constexpr int ROWP      = 3 * CH + 3 * CIN + 8;   // 3464 elems, 6928 B (pitch%128B=16 -> 2-way banks)
static constexpr int WS_BYTES  = 16 * ROWP * 2;          // 110848
static constexpr int RED_BYTES = 4 * 32 * 33 * 4;        // 16896
static constexpr int ZL_BYTES  = 2 * CZ * 4;             // 1024
static constexpr int SMEM_BYTES = WS_BYTES + RED_BYTES + ZL_BYTES;  // 128768

#define DEV static __device__ __forceinline__

DEV float sigmoidf_(float x) { return 1.0f / (1.0f + expf(-x)); }
DEV float softplusf_(float x) { return x > 20.0f ? x : log1pf(expf(x)); }
DEV bf16x8 ldfrag(const bf16* p) { return *reinterpret_cast<const bf16x8*>(p); }

#define MFMA(a, b, c) __builtin_amdgcn_mfma_f32_16x16x32_bf16((a), (b), (c), 0, 0, 0)

// ---- relaxed agent-scope access helpers (proven r4/r5) ----
DEV u64 lda8(const void* p) {
    return __hip_atomic_load((const u64*)p, __ATOMIC_RELAXED, __HIP_MEMORY_SCOPE_AGENT);
}
DEV void sta8(void* p, u64 v) {
    __hip_atomic_store((u64*)p, v, __ATOMIC_RELAXED, __HIP_MEMORY_SCOPE_AGENT);
}
DEV u32 lda4(const void* p) {
    return __hip_atomic_load((const u32*)p, __ATOMIC_RELAXED, __HIP_MEMORY_SCOPE_AGENT);
}
DEV void sta4(void* p, u32 v) {
    __hip_atomic_store((u32*)p, v, __ATOMIC_RELAXED, __HIP_MEMORY_SCOPE_AGENT);
}
DEV bf16x8 ld_act16(const bf16* p) {
    union { u64 u[2]; bf16x8 v; } r;
    r.u[0] = lda8(p);
    r.u[1] = lda8((const char*)p + 8);
    return r.v;
}
DEV u32 pk2(float a, float b) {
    union { bf16 h[2]; u32 u; } r;
    r.h[0] = (bf16)a; r.h[1] = (bf16)b;
    return r.u;
}

struct Prm {
    const float *eps_q, *eps_p;
    const float *bih_q, *bhh_q, *bd_q, *bmu_q, *bsig_q;
    const float *Wp, *bp, *up, *Wlg, *blg;
    const float *bih_p, *bhh_p, *bd_p, *bmu_p, *bsig_p;
    const bf16 *x_b, *Wih_qb, *Whh_qb, *Wd_qb, *Wmu_qb, *Wsg_qb;
    const bf16 *Wih_pb, *Whh_pb, *Wd_pb, *Wmu_pb, *Wsg_pb;
    float *e_f0, *e_f1; bf16 *e_b0, *e_b1;
    float *d_f0, *d_f1; bf16 *d_b0, *d_b1;
    float *ztmp_f;
    bf16 *dvec_b, *ddvec_b;
    bf16 *zflow;    // [CW+1][CB][CZ], slot 0 zeroed
    bf16 *ztlg;     // [CW][CB][CZ]
    u32 *barQ, *barP, *zbar;   // 128 each
    float *out_o, *out_mu, *out_lv;
};

// ---------------------------------------------------------------------------
// Per-half fence-free barrier over 128 WGs (flag array, vmcnt drain).
// ---------------------------------------------------------------------------
DEV void gbar_h(u32* bar, int wgl, u32 k)
{
    asm volatile("s_waitcnt vmcnt(0)" ::: "memory");
    __syncthreads();
    if (threadIdx.x == 0)
        __hip_atomic_store(&bar[wgl], k, __ATOMIC_RELAXED, __HIP_MEMORY_SCOPE_AGENT);
    if (threadIdx.x < 128) {
        while (__hip_atomic_load(&bar[threadIdx.x], __ATOMIC_RELAXED,
                                 __HIP_MEMORY_SCOPE_AGENT) < k)
            __builtin_amdgcn_s_sleep(4);
    }
    __syncthreads();
}

// ---------------------------------------------------------------------------
__global__ void k_cvt(const float* __restrict__ src, bf16* __restrict__ dst, int n)
{
    int i = (blockIdx.x * blockDim.x + threadIdx.x) * 4;
    if (i < n) {
        float4 v = *reinterpret_cast<const float4*>(src + i);
        bf16x4 o;
        o[0] = (bf16)v.x; o[1] = (bf16)v.y; o[2] = (bf16)v.z; o[3] = (bf16)v.w;
        *reinterpret_cast<bf16x4*>(dst + i) = o;
    }
}

// ---------------------------------------------------------------------------
// GRU phase, weight-stationary: WG (ms = wgl>>6, ns = wgl&63) computes
// rows [ms*128, ms*128+128) x cols [ns*16, ns*16+16). Each wave owns 2 m-frags
// and runs the FULL K (no cross-wave reduce). Weights from LDS.
// ---------------------------------------------------------------------------
DEV void phase_gru2(int wgl, int lane, int wave, int lr, int lkE, const bf16* WS,
                    const bf16* __restrict__ Xin, long xstride, int xagent,
                    const bf16* __restrict__ Ebin, const float* __restrict__ Efin,
                    const float* __restrict__ bih, const float* __restrict__ bhh,
                    float* __restrict__ Efo, bf16* __restrict__ Ebo)
{
    const int ns = wgl & 63, ms = wgl >> 6;
    const int n0 = ns * 16;
    const int rA0 = ms * 128 + wave * 32 + lr;
    const int rA1 = rA0 + 16;
    const bf16* wsrow = WS + (long)lr * ROWP;

    f32x4 acc[4][2] = {};   // [group r/z/ni/nh][frag]

    // input part K = 128
#pragma unroll
    for (int k = 0; k < CIN; k += 32) {
        bf16x8 a0, a1;
        if (xagent) {
            a0 = ld_act16(Xin + (long)rA0 * xstride + k + lkE);
            a1 = ld_act16(Xin + (long)rA1 * xstride + k + lkE);
        } else {
            a0 = ldfrag(Xin + (long)rA0 * xstride + k + lkE);
            a1 = ldfrag(Xin + (long)rA1 * xstride + k + lkE);
        }
#pragma unroll
        for (int g = 0; g < 3; ++g) {
            bf16x8 b = *reinterpret_cast<const bf16x8*>(wsrow + 3 * CH + g * CIN + k + lkE);
            const int grp = (g == 2) ? 2 : g;
            acc[grp][0] = MFMA(a0, b, acc[grp][0]);
            acc[grp][1] = MFMA(a1, b, acc[grp][1]);
        }
    }
    // hidden part K = 1024
#pragma unroll 4
    for (int k = 0; k < CH; k += 32) {
        bf16x8 a0 = ld_act16(Ebin + (long)rA0 * CH + k + lkE);
        bf16x8 a1 = ld_act16(Ebin + (long)rA1 * CH + k + lkE);
#pragma unroll
        for (int g = 0; g < 3; ++g) {
            bf16x8 b = *reinterpret_cast<const bf16x8*>(wsrow + g * CH + k + lkE);
            const int grp = (g == 2) ? 3 : g;
            acc[grp][0] = MFMA(a0, b, acc[grp][0]);
            acc[grp][1] = MFMA(a1, b, acc[grp][1]);
        }
    }

    // epilogue: C frag mapping row=(lane>>4)*4+i, col=lane&15 (HW-verified)
    const int col = n0 + lr;
    const float b0r = bih[col] + bhh[col];
    const float b0z = bih[CH + col] + bhh[CH + col];
    const float bin = bih[2 * CH + col];
    const float bhn = bhh[2 * CH + col];
#pragma unroll
    for (int f = 0; f < 2; ++f) {
        const int rbase = ms * 128 + wave * 32 + f * 16 + (lane >> 4) * 4;
#pragma unroll
        for (int i = 0; i < 4; ++i) {
            const int row = rbase + i;
            float gr = acc[0][f][i] + b0r;
            float gz = acc[1][f][i] + b0z;
            float gi = acc[2][f][i] + bin;
            float gh = acc[3][f][i] + bhn;
            float r = sigmoidf_(gr);
            float u = sigmoidf_(gz);
            float n = tanhf(gi + r * gh);
            float en = (1.0f - u) * n + u * Efin[(long)row * CH + col];
            Efo[(long)row * CH + col] = en;           // owner-thread fp32 master
            float vB = __shfl_xor(en, 1);
            if (!(lane & 1))
                sta4(Ebo + (long)row * CH + col, pk2(en, vB));
        }
    }
}

// ---------------------------------------------------------------------------
// Linear phase (weight rows from global/L2): same WG tiling as GRU.
// A1 (K=128, optional) then A2 (K=1024), both agent-scope.
// ---------------------------------------------------------------------------
DEV void phase_lin2(int wgl, int lane, int wave, int lr, int lkE,
                    const bf16* __restrict__ A1, long a1s,
                    const bf16* __restrict__ A2,
                    const bf16* __restrict__ W, int ldw,
                    const float* __restrict__ bias, bf16* __restrict__ Out)
{
    const int ns = wgl & 63, ms = wgl >> 6;
    const int n0 = ns * 16;
    const int rA0 = ms * 128 + wave * 32 + lr;
    const int rA1 = rA0 + 16;
    const bf16* wrow = W + (long)(n0 + lr) * ldw;

    f32x4 acc[2] = {};
    int koff = 0;
    if (A1) {
#pragma unroll
        for (int k = 0; k < CZ; k += 32) {
            bf16x8 a0 = ld_act16(A1 + (long)rA0 * a1s + k + lkE);
            bf16x8 a1 = ld_act16(A1 + (long)rA1 * a1s + k + lkE);
            bf16x8 b  = ldfrag(wrow + k + lkE);
            acc[0] = MFMA(a0, b, acc[0]);
            acc[1] = MFMA(a1, b, acc[1]);
        }
        koff = CZ;
    }
#pragma unroll 4
    for (int k = 0; k < CH; k += 32) {
        bf16x8 a0 = ld_act16(A2 + (long)rA0 * CH + k + lkE);
        bf16x8 a1 = ld_act16(A2 + (long)rA1 * CH + k + lkE);
        bf16x8 b  = ldfrag(wrow + koff + k + lkE);
        acc[0] = MFMA(a0, b, acc[0]);
        acc[1] = MFMA(a1, b, acc[1]);
    }

    const int col = n0 + lr;
    const float bb = bias[col];
#pragma unroll
    for (int f = 0; f < 2; ++f) {
        const int rbase = ms * 128 + wave * 32 + f * 16 + (lane >> 4) * 4;
#pragma unroll
        for (int i = 0; i < 4; ++i) {
            float v = acc[f][i] + bb;
            float vB = __shfl_xor(v, 1);
            if (!(lane & 1))
                sta4(Out + (long)(rbase + i) * CD + col, pk2(v, vB));
        }
    }
}

// ---------------------------------------------------------------------------
// Two-head tail (128 WGs of a half): 16x16 tile, both heads, 4-wave K-split
// with LDS reduce (r5-proven structure). MODE 0: qnet; MODE 1: pnet.
// ---------------------------------------------------------------------------
template <int MODE>
DEV void phase_tail2(const Prm& p, int t, int wgl, int lane, int wave, int lr, int lkE,
                     float* REDp, const bf16* __restrict__ A,
                     const bf16* __restrict__ Wa, const bf16* __restrict__ Wb,
                     const float* __restrict__ ba, const float* __restrict__ bb)
{
    const int mb = (wgl >> 3) << 4;   // 0..240
    const int nb = (wgl & 7) << 4;    // 0..112
    f32x4 am = {}, as = {};
    const int k0 = wave * 256;
#pragma unroll 2
    for (int kk = 0; kk < 256; kk += 32) {
        const int k = k0 + kk;
        bf16x8 a  = ld_act16(A + (long)(mb + lr) * CD + k + lkE);
        bf16x8 bm = ldfrag(Wa + (long)(nb + lr) * CD + k + lkE);
        bf16x8 bs = ldfrag(Wb + (long)(nb + lr) * CD + k + lkE);
        am = MFMA(a, bm, am);
        as = MFMA(a, bs, as);
    }
    const int tid2 = wave * 64 + lane;
    const int trow = tid2 >> 4, tcol = tid2 & 15;
    auto R = [&](int w, int r, int c) -> float& { return REDp[(w * 32 + r) * 33 + c]; };
    __syncthreads();
#pragma unroll
    for (int i = 0; i < 4; ++i) R(wave, (lane >> 4) * 4 + i, lr) = am[i];
    __syncthreads();
    float vm = R(0, trow, tcol) + R(1, trow, tcol) + R(2, trow, tcol) + R(3, trow, tcol);
    __syncthreads();
#pragma unroll
    for (int i = 0; i < 4; ++i) R(wave, (lane >> 4) * 4 + i, lr) = as[i];
    __syncthreads();
    float vs = R(0, trow, tcol) + R(1, trow, tcol) + R(2, trow, tcol) + R(3, trow, tcol);

    const int row = mb + trow, col = nb + tcol;
    if constexpr (MODE == 0) {
        float mu = vm + ba[col];
        float lv = softplusf_(vs + bb[col]);
        float e  = p.eps_q[(long)row * CW * CZ + (long)t * CZ + col];
        float z  = mu + expf(0.5f * lv) * e;
        p.out_mu[(long)row * CW * CZ + (long)t * CZ + col] = mu;
        p.out_lv[(long)row * CW * CZ + (long)t * CZ + col] = lv;
        sta4(p.ztmp_f + (long)row * CZ + col, __float_as_uint(z));
    } else {
        float m  = vm + ba[col];
        float sg = softplusf_(vs + bb[col]);
        float e  = p.eps_p[(long)row * CW * COUT + (long)t * COUT + col];
        p.out_o[(long)row * CW * COUT + (long)t * COUT + col] = m + sg * e;
    }
}

// ---------------------------------------------------------------------------
// Planar flows + LGSSM linear (Q half, 2 batch rows per WG, fp32).
// Publishes zflow[t+1] (next-step lin input) and ztlg[t] (Pnet GRU input).
// ---------------------------------------------------------------------------
DEV void phase_flows2(const Prm& p, int wgl, int tid, int t, float* zl)
{
    const int r = tid >> 7, c = tid & 127;
    const int row = wgl * 2 + r;
    float* zrow = zl + r * CZ;

    zrow[c] = __uint_as_float(lda4(p.ztmp_f + (long)row * CZ + c));
    __syncthreads();

#pragma unroll 1
    for (int kf = 0; kf < 3; ++kf) {
        const float* wr = p.Wp + ((long)kf * CZ + c) * CZ;
        float s = p.bp[kf * CZ + c];
#pragma unroll 8
        for (int j = 0; j < CZ; j += 4) {
            float4 w  = *reinterpret_cast<const float4*>(wr + j);
            float4 z4 = *reinterpret_cast<const float4*>(zrow + j);
            s += z4.x * w.x + z4.y * w.y + z4.z * w.z + z4.w * w.w;
        }
        float nz = zrow[c] + p.up[kf] * tanhf(s);
        __syncthreads();
        zrow[c] = nz;
        __syncthreads();
    }
    // zt = z @ Wlg^T + blg
    const float* wr = p.Wlg + (long)c * CZ;
    float s = p.blg[c];
#pragma unroll 8
    for (int j = 0; j < CZ; j += 4) {
        float4 w  = *reinterpret_cast<const float4*>(wr + j);
        float4 z4 = *reinterpret_cast<const float4*>(zrow + j);
        s += z4.x * w.x + z4.y * w.y + z4.z * w.z + z4.w * w.w;
    }
    float sB = __shfl_xor(s, 1);
    if (!(tid & 1)) {
        sta4(p.ztlg  + ((size_t)t * CB + row) * CZ + c, pk2(s, sB));
        sta4(p.zflow + ((size_t)(t + 1) * CB + row) * CZ + c, pk2(zrow[c], zrow[c + 1]));
    }
}

// ---------------------------------------------------------------------------
// Mega kernel.
// ---------------------------------------------------------------------------
__launch_bounds__(256)
__global__ void mega(Prm p)
{
    extern __shared__ char smem[];
    bf16*  WS   = (bf16*)smem;
    float* REDp = (float*)(smem + WS_BYTES);
    float* ZLp  = (float*)(smem + WS_BYTES + RED_BYTES);

    const int wg = blockIdx.x, tid = threadIdx.x;
    const int lane = tid & 63, wave = tid >> 6;
    const int lr = lane & 15, lkE = (lane >> 4) * 8;
    const bool isQ = wg < 128;
    const int wgl = isQ ? wg : wg - 128;

    // ---- preload GRU weight slice into LDS (once) ----
    {
        const bf16* Whh = isQ ? p.Whh_qb : p.Whh_pb;
        const bf16* Wih = isQ ? p.Wih_qb : p.Wih_pb;
        const int ns = wgl & 63;
        const int kk = tid * 8;
        for (int r = 0; r < 16; ++r) {
#pragma unroll
            for (int g = 0; g < 3; ++g) {
                if (kk < CH)
                    *reinterpret_cast<bf16x8*>(&WS[(long)r * ROWP + g * CH + kk]) =
                        ldfrag(Whh + ((long)g * CH + ns * 16 + r) * CH + kk);
                if (kk < CIN)
                    *reinterpret_cast<bf16x8*>(&WS[(long)r * ROWP + 3 * CH + g * CIN + kk]) =
                        ldfrag(Wih + ((long)g * CH + ns * 16 + r) * CIN + kk);
            }
        }
        __syncthreads();
    }

    if (isQ) {
        u32 bk = 0;
#pragma unroll 1
        for (int t = 0; t < CW; ++t) {
            const int bi = t & 1;
            const bf16*  eb_i = bi ? p.e_b1 : p.e_b0;
            const float* ef_i = bi ? p.e_f1 : p.e_f0;
            bf16*  eb_o = bi ? p.e_b0 : p.e_b1;
            float* ef_o = bi ? p.e_f0 : p.e_f1;

            phase_gru2(wgl, lane, wave, lr, lkE, WS,
                       p.x_b + (long)t * CIN, (long)CW * CIN, 0,
                       eb_i, ef_i, p.bih_q, p.bhh_q, ef_o, eb_o);
            gbar_h(p.barQ, wgl, ++bk);
            phase_lin2(wgl, lane, wave, lr, lkE,
                       p.zflow + (size_t)t * CB * CZ, CZ,
                       eb_o, p.Wd_qb, CZ + CH, p.bd_q, p.dvec_b);
            gbar_h(p.barQ, wgl, ++bk);
            phase_tail2<0>(p, t, wgl, lane, wave, lr, lkE, REDp,
                           p.dvec_b, p.Wmu_qb, p.Wsg_qb, p.bmu_q, p.bsig_q);
            gbar_h(p.barQ, wgl, ++bk);
            phase_flows2(p, wgl, tid, t, ZLp);
            // publish z availability (mini-publish, no full barrier)
            asm volatile("s_waitcnt vmcnt(0)" ::: "memory");
            __syncthreads();
            if (tid == 0)
                __hip_atomic_store(&p.zbar[wgl], (u32)(t + 1),
                                   __ATOMIC_RELAXED, __HIP_MEMORY_SCOPE_AGENT);
            __syncthreads();
        }
    } else {
        u32 bk = 0;
#pragma unroll 1
        for (int t = 0; t < CW; ++t) {
            // wait for z(t) from Q half
            if (tid < 128) {
                while (__hip_atomic_load(&p.zbar[tid], __ATOMIC_RELAXED,
                                         __HIP_MEMORY_SCOPE_AGENT) < (u32)(t + 1))
                    __builtin_amdgcn_s_sleep(8);
            }
            __syncthreads();

            const int bi = t & 1;
            const bf16*  db_i = bi ? p.d_b1 : p.d_b0;
            const float* df_i = bi ? p.d_f1 : p.d_f0;
            bf16*  db_o = bi ? p.d_b0 : p.d_b1;
            float* df_o = bi ? p.d_f0 : p.d_f1;

            phase_gru2(wgl, lane, wave, lr, lkE, WS,
                       p.ztlg + (size_t)t * CB * CZ, CZ, 1,
                       db_i, df_i, p.bih_p, p.bhh_p, df_o, db_o);
            gbar_h(p.barP, wgl, ++bk);
            phase_lin2(wgl, lane, wave, lr, lkE,
                       nullptr, 0, db_o, p.Wd_pb, CH, p.bd_p, p.ddvec_b);
            gbar_h(p.barP, wgl, ++bk);
            phase_tail2<1>(p, t, wgl, lane, wave, lr, lkE, REDp,
                           p.ddvec_b, p.Wmu_pb, p.Wsg_pb, p.bmu_p, p.bsig_p);
            // no barrier: ddvec reuse protected by next barP after GRU(t+1)
        }
    }
}

// ---------------------------------------------------------------------------
// Host driver
// ---------------------------------------------------------------------------
extern "C" void kernel_launch(void* const* d_in, const int* in_sizes, int n_in,
                              void* d_out, int out_size, void* d_ws, size_t ws_size,
                              hipStream_t stream)
{
    Prm p;
    const float* x      = (const float*)d_in[0];
    p.eps_q  = (const float*)d_in[1];
    p.eps_p  = (const float*)d_in[2];
    const float* Wih_q  = (const float*)d_in[3];
    const float* Whh_q  = (const float*)d_in[4];
    p.bih_q  = (const float*)d_in[5];
    p.bhh_q  = (const float*)d_in[6];
    const float* Wd_q   = (const float*)d_in[7];
    p.bd_q   = (const float*)d_in[8];
    const float* Wmu_q  = (const float*)d_in[9];
    p.bmu_q  = (const float*)d_in[10];
    const float* Wsig_q = (const float*)d_in[11];
    p.bsig_q = (const float*)d_in[12];
    p.Wp     = (const float*)d_in[13];
    p.bp     = (const float*)d_in[14];
    p.up     = (const float*)d_in[15];
    p.Wlg    = (const float*)d_in[16];
    p.blg    = (const float*)d_in[17];
    const float* Wih_p  = (const float*)d_in[18];
    const float* Whh_p  = (const float*)d_in[19];
    p.bih_p  = (const float*)d_in[20];
    p.bhh_p  = (const float*)d_in[21];
    const float* Wd_p   = (const float*)d_in[22];
    p.bd_p   = (const float*)d_in[23];
    const float* Wmu_p  = (const float*)d_in[24];
    p.bmu_p  = (const float*)d_in[25];
    const float* Wsig_p = (const float*)d_in[26];
    p.bsig_p = (const float*)d_in[27];

    p.out_o  = (float*)d_out;
    p.out_mu = p.out_o + (size_t)CB * CW * COUT;
    p.out_lv = p.out_mu + (size_t)CB * CW * CZ;

    char* wp_ = (char*)d_ws;
    auto carve = [&](size_t bytes) -> void* {
        void* q = (void*)wp_;
        wp_ += (bytes + 255) & ~(size_t)255;
        return q;
    };
    p.e_f0 = (float*)carve((size_t)CB * CH * 4);
    p.e_f1 = (float*)carve((size_t)CB * CH * 4);
    p.e_b0 = (bf16*)carve((size_t)CB * CH * 2);
    p.e_b1 = (bf16*)carve((size_t)CB * CH * 2);
    p.d_f0 = (float*)carve((size_t)CB * CH * 4);
    p.d_f1 = (float*)carve((size_t)CB * CH * 4);
    p.d_b0 = (bf16*)carve((size_t)CB * CH * 2);
    p.d_b1 = (bf16*)carve((size_t)CB * CH * 2);
    p.ztmp_f  = (float*)carve((size_t)CB * CZ * 4);
    p.dvec_b  = (bf16*)carve((size_t)CB * CD * 2);
    p.ddvec_b = (bf16*)carve((size_t)CB * CD * 2);
    p.zflow   = (bf16*)carve((size_t)(CW + 1) * CB * CZ * 2);
    p.ztlg    = (bf16*)carve((size_t)CW * CB * CZ * 2);
    p.barQ    = (u32*)carve(512);
    p.barP    = (u32*)carve(512);
    p.zbar    = (u32*)carve(512);
    bf16* x_b    = (bf16*)carve((size_t)CB * CW * CIN * 2);
    bf16* Wih_qb = (bf16*)carve((size_t)3 * CH * CIN * 2);
    bf16* Whh_qb = (bf16*)carve((size_t)3 * CH * CH * 2);
    bf16* Wd_qb  = (bf16*)carve((size_t)CD * (CZ + CH) * 2);
    bf16* Wmu_qb = (bf16*)carve((size_t)CZ * CD * 2);
    bf16* Wsg_qb = (bf16*)carve((size_t)CZ * CD * 2);
    bf16* Wih_pb = (bf16*)carve((size_t)3 * CH * CZ * 2);
    bf16* Whh_pb = (bf16*)carve((size_t)3 * CH * CH * 2);
    bf16* Wd_pb  = (bf16*)carve((size_t)CD * CH * 2);
    bf16* Wmu_pb = (bf16*)carve((size_t)COUT * CD * 2);
    bf16* Wsg_pb = (bf16*)carve((size_t)COUT * CD * 2);
    p.x_b = x_b;       p.Wih_qb = Wih_qb; p.Whh_qb = Whh_qb;
    p.Wd_qb = Wd_qb;   p.Wmu_qb = Wmu_qb; p.Wsg_qb = Wsg_qb;
    p.Wih_pb = Wih_pb; p.Whh_pb = Whh_pb; p.Wd_pb = Wd_pb;
    p.Wmu_pb = Wmu_pb; p.Wsg_pb = Wsg_pb;

    hipMemsetAsync(p.e_f0, 0, (size_t)CB * CH * 4, stream);
    hipMemsetAsync(p.e_b0, 0, (size_t)CB * CH * 2, stream);
    hipMemsetAsync(p.d_f0, 0, (size_t)CB * CH * 4, stream);
    hipMemsetAsync(p.d_b0, 0, (size_t)CB * CH * 2, stream);
    hipMemsetAsync(p.zflow, 0, (size_t)CB * CZ * 2, stream);   // slot 0 = zeros
    hipMemsetAsync(p.barQ, 0, 512, stream);
    hipMemsetAsync(p.barP, 0, 512, stream);
    hipMemsetAsync(p.zbar, 0, 512, stream);

    auto cvt = [&](const float* s, bf16* d, size_t n) {
        k_cvt<<<dim3((unsigned)((n / 4 + 255) / 256)), dim3(256), 0, stream>>>(s, d, (int)n);
    };
    cvt(x,      x_b,    (size_t)CB * CW * CIN);
    cvt(Wih_q,  Wih_qb, (size_t)3 * CH * CIN);
    cvt(Whh_q,  Whh_qb, (size_t)3 * CH * CH);
    cvt(Wd_q,   Wd_qb,  (size_t)CD * (CZ + CH));
    cvt(Wmu_q,  Wmu_qb, (size_t)CZ * CD);
    cvt(Wsig_q, Wsg_qb, (size_t)CZ * CD);
    cvt(Wih_p,  Wih_pb, (size_t)3 * CH * CZ);
    cvt(Whh_p,  Whh_pb, (size_t)3 * CH * CH);
    cvt(Wd_p,   Wd_pb,  (size_t)CD * CH);
    cvt(Wmu_p,  Wmu_pb, (size_t)COUT * CD);
    cvt(Wsig_p, Wsg_pb, (size_t)COUT * CD);

    static bool attr_set = false;
    if (!attr_set) {
        hipFuncSetAttribute((const void*)mega,
                            hipFuncAttributeMaxDynamicSharedMemorySize, SMEM_BYTES);
        attr_set = true;
    }
    mega<<<dim3(256), dim3(256), SMEM_BYTES, stream>>>(p);
}